// Round 8
// baseline (2353.425 us; speedup 1.0000x reference)
//
#include <hip/hip_runtime.h>
#include <hip/hip_bf16.h>

// GCN: h = relu(GCN(x,W1,b1)); h = relu(GCN(h,W2,b2)); out = h @ Wfc + bfc
// GCN(x,W,b)[d] = dis[d] * ( sum_{(s,d) in E} hs[s] + hs[d] ) + b
//   where hs[v] = (x[v]@W) * dis[v],  dis[v] = rsqrt(1 + indeg(v))
//
// Structure (round 8): binned counting sort -> per-bucket src-sorted edge
// list (L2 wavefront; round-7 measured FETCH 364->240 MB).  Aggregation =
// per-bucket LDS accumulators, 8 edges in flight per wave (fixes round-7's
// MLP=1 latency collapse).  gemm2 fused into agg1 epilogue, FC into agg2.

#define SCAN_CHUNK 1024
#define BSHIFT 7
#define BSIZE 128            // dsts per bucket
#define B1 256               // blocks in hist/binscatter passes
#define STA 68               // acc stride for 64-f rows (float4-aligned)
#define STB 36               // acc stride for 32-f rows

__device__ inline void f4fma(float4& a, float s, const float4& b) {
    a.x = fmaf(s, b.x, a.x); a.y = fmaf(s, b.y, a.y);
    a.z = fmaf(s, b.z, a.z); a.w = fmaf(s, b.w, a.w);
}

// ---- generic exclusive scan (m ints, nblk = ceil(m/1024) <= 256) ----
__global__ void k_gscan1(const int* __restrict__ in, int* __restrict__ part, int m) {
    int t = threadIdx.x;
    int base = blockIdx.x * SCAN_CHUNK + t * 4;
    int s = 0;
    for (int u = 0; u < 4; ++u) { int i = base + u; if (i < m) s += in[i]; }
    for (int o = 32; o; o >>= 1) s += __shfl_down(s, o);
    __shared__ int ws[4];
    if ((t & 63) == 0) ws[t >> 6] = s;
    __syncthreads();
    if (t == 0) part[blockIdx.x] = ws[0] + ws[1] + ws[2] + ws[3];
}

__global__ void k_gscan2(const int* __restrict__ in, const int* __restrict__ part,
                         int* __restrict__ out, int m, int nblk) {
    int t = threadIdx.x;
    int b = blockIdx.x;
    int pv = (t < b && t < nblk) ? part[t] : 0;
    int ps = pv;
    for (int o = 32; o; o >>= 1) ps += __shfl_down(ps, o);
    __shared__ int sh[4];
    if ((t & 63) == 0) sh[t >> 6] = ps;
    __syncthreads();
    int blockoff = sh[0] + sh[1] + sh[2] + sh[3];

    int base = b * SCAN_CHUNK + t * 4;
    int v0 = 0, v1 = 0, v2 = 0, v3 = 0;
    if (base + 0 < m) v0 = in[base + 0];
    if (base + 1 < m) v1 = in[base + 1];
    if (base + 2 < m) v2 = in[base + 2];
    if (base + 3 < m) v3 = in[base + 3];
    int tot = v0 + v1 + v2 + v3;
    int lane = t & 63, wid = t >> 6;
    int incl = tot;
    for (int o = 1; o < 64; o <<= 1) { int u = __shfl_up(incl, o); if (lane >= o) incl += u; }
    int excl = incl - tot;
    __shared__ int wt[4];
    if (lane == 63) wt[wid] = incl;
    __syncthreads();
    int woff = 0;
    for (int w = 0; w < wid; ++w) woff += wt[w];
    int off = blockoff + woff + excl;
    if (base + 0 < m) out[base + 0] = off;
    if (base + 1 < m) out[base + 1] = off + v0;
    if (base + 2 < m) out[base + 2] = off + v0 + v1;
    if (base + 3 < m) out[base + 3] = off + v0 + v1 + v2;
}

// ---- pass 1a: per-block bucket histogram (LDS atomics only) ----
__global__ __launch_bounds__(256) void k_hist(const int* __restrict__ dst,
                                              int* __restrict__ ghist,
                                              int e, int echunk, int nbuck) {
    extern __shared__ int h[];   // nbuck ints
    int t = threadIdx.x, b = blockIdx.x;
    for (int i = t; i < nbuck; i += 256) h[i] = 0;
    __syncthreads();
    int s = b * echunk, epd = min(e, s + echunk);
    for (int i = s + t; i < epd; i += 256)
        atomicAdd(&h[dst[i] >> BSHIFT], 1);
    __syncthreads();
    for (int k = t; k < nbuck; k += 256)
        ghist[k * B1 + b] = h[k];
}

// ---- pass 1b: scatter packed (src<<7|dlow) into bucket-ordered ebuf ----
__global__ __launch_bounds__(256) void k_binscatter(
        const int* __restrict__ src, const int* __restrict__ dst,
        const int* __restrict__ ghist_s, int* __restrict__ ebuf,
        int e, int echunk, int nbuck) {
    extern __shared__ int cur[];   // nbuck ints
    int t = threadIdx.x, b = blockIdx.x;
    for (int k = t; k < nbuck; k += 256)
        cur[k] = ghist_s[k * B1 + b];
    __syncthreads();
    int s = b * echunk, epd = min(e, s + echunk);
    for (int i = s + t; i < epd; i += 256) {
        int d = dst[i];
        int pos = atomicAdd(&cur[d >> BSHIFT], 1);
        ebuf[pos] = (src[i] << BSHIFT) | (d & (BSIZE - 1));
    }
}

// ---- pass 2: per-bucket counting sort by src bin + dis computation ----
__global__ __launch_bounds__(256) void k_sort(
        const int* __restrict__ ebuf, const int* __restrict__ ghist_s,
        int* __restrict__ ebuf2, float* __restrict__ dis,
        int n, int e, int nbuck, int sshift) {
    int k = blockIdx.x, t = threadIdx.x;
    int estart = ghist_s[k * B1];
    int eend = (k + 1 < nbuck) ? ghist_s[(k + 1) * B1] : e;
    __shared__ int hist[256];
    __shared__ int cur2[256];
    __shared__ int dcnt[BSIZE];
    __shared__ int wt[4];
    hist[t] = 0;
    if (t < BSIZE) dcnt[t] = 0;
    __syncthreads();
    for (int i = estart + t; i < eend; i += 256) {
        int w = ebuf[i];
        atomicAdd(&hist[(((unsigned)w) >> BSHIFT) >> sshift], 1);
        atomicAdd(&dcnt[w & (BSIZE - 1)], 1);
    }
    __syncthreads();
    if (t < BSIZE) {
        int node = k * BSIZE + t;
        if (node < n) dis[node] = rsqrtf((float)(dcnt[t] + 1));
    }
    int v = hist[t];
    int lane = t & 63, wid = t >> 6;
    int incl = v;
    for (int o = 1; o < 64; o <<= 1) { int u = __shfl_up(incl, o); if (lane >= o) incl += u; }
    if (lane == 63) wt[wid] = incl;
    __syncthreads();
    int woff = 0;
    for (int w = 0; w < wid; ++w) woff += wt[w];
    cur2[t] = estart + woff + incl - v;
    __syncthreads();
    for (int i = estart + t; i < eend; i += 256) {
        int w = ebuf[i];
        int pos = atomicAdd(&cur2[(((unsigned)w) >> BSHIFT) >> sshift], 1);
        ebuf2[pos] = w;
    }
}

// h1s = (x @ W1) * dis — outer-product GEMM, block tile 64x64, K=128.
#define SA 132
__global__ __launch_bounds__(256) void k_gemm1(
        const float* __restrict__ x, const float* __restrict__ W1,
        const float* __restrict__ dis, float* __restrict__ h1s, int n) {
    __shared__ float Xs[64 * SA];    // 33 KB
    __shared__ float Ws[128 * 64];   // 32 KB
    int t = threadIdx.x;
    int nbase = blockIdx.x * 64;
    for (int i = t; i < 2048; i += 256)
        ((float4*)Ws)[i] = ((const float4*)W1)[i];
    for (int i = t; i < 2048; i += 256) {
        int row = i >> 5, q = i & 31;
        int r = nbase + row; if (r >= n) r = n - 1;
        float4 v = ((const float4*)(x + (size_t)r * 128))[q];
        *(float4*)&Xs[row * SA + q * 4] = v;
    }
    __syncthreads();
    int wid = t >> 6, lane = t & 63;
    int lx = lane & 7, ly = lane >> 3;
    int wm = wid & 1, wn = wid >> 1;
    int row0 = wm * 32 + ly * 4;
    int col0 = wn * 32 + lx * 4;
    float4 acc0 = {0.f,0.f,0.f,0.f}, acc1 = acc0, acc2 = acc0, acc3 = acc0;
#pragma unroll 4
    for (int k4 = 0; k4 < 32; ++k4) {
        int k = k4 * 4;
        float4 a0 = *(const float4*)&Xs[(row0 + 0) * SA + k];
        float4 a1 = *(const float4*)&Xs[(row0 + 1) * SA + k];
        float4 a2 = *(const float4*)&Xs[(row0 + 2) * SA + k];
        float4 a3 = *(const float4*)&Xs[(row0 + 3) * SA + k];
        float4 b0 = *(const float4*)&Ws[(k + 0) * 64 + col0];
        float4 b1 = *(const float4*)&Ws[(k + 1) * 64 + col0];
        float4 b2 = *(const float4*)&Ws[(k + 2) * 64 + col0];
        float4 b3 = *(const float4*)&Ws[(k + 3) * 64 + col0];
        f4fma(acc0, a0.x, b0); f4fma(acc0, a0.y, b1); f4fma(acc0, a0.z, b2); f4fma(acc0, a0.w, b3);
        f4fma(acc1, a1.x, b0); f4fma(acc1, a1.y, b1); f4fma(acc1, a1.z, b2); f4fma(acc1, a1.w, b3);
        f4fma(acc2, a2.x, b0); f4fma(acc2, a2.y, b1); f4fma(acc2, a2.z, b2); f4fma(acc2, a2.w, b3);
        f4fma(acc3, a3.x, b0); f4fma(acc3, a3.y, b1); f4fma(acc3, a3.z, b2); f4fma(acc3, a3.w, b3);
    }
    int grow = nbase + row0;
#pragma unroll
    for (int r = 0; r < 4; ++r) {
        int rr = grow + r;
        if (rr < n) {
            float d = dis[rr];
            float4 o = (r == 0) ? acc0 : (r == 1) ? acc1 : (r == 2) ? acc2 : acc3;
            o.x *= d; o.y *= d; o.z *= d; o.w *= d;
            *(float4*)&h1s[(size_t)rr * 64 + col0] = o;
        }
    }
}

// layer-1 aggregation (LDS acc, src-sorted edges, 8 edges in flight per
// wave) fused with relu+b1 and gemm2 -> h2s.
__global__ __launch_bounds__(256) void k_agg1f(
        const float* __restrict__ h1s, const int* __restrict__ ebuf2,
        const int* __restrict__ ghist_s, const float* __restrict__ dis,
        const float* __restrict__ b1, const float* __restrict__ W2,
        float* __restrict__ h2s, int n, int e, int nbuck) {
    __shared__ float accA[BSIZE * STA];   // 34816 B
    __shared__ float Ws[64 * 32];         // 8 KB
    __shared__ float disS[BSIZE];
    __shared__ float b1S[64];
    int k = blockIdx.x, t = threadIdx.x;
    int estart = ghist_s[k * B1];
    int eend = (k + 1 < nbuck) ? ghist_s[(k + 1) * B1] : e;
    int nb = k * BSIZE;
    for (int i = t; i < 512; i += 256)
        ((float4*)Ws)[i] = ((const float4*)W2)[i];
    if (t < 64) b1S[t] = b1[t];
    if (t < BSIZE) disS[t] = dis[min(nb + t, n - 1)];
    for (int i = t; i < 2048; i += 256) {
        int row = i >> 4, q = i & 15;
        int node = nb + row; if (node >= n) node = n - 1;
        float4 v = ((const float4*)(h1s + (size_t)node * 64))[q];
        *(float4*)&accA[row * STA + q * 4] = v;      // self-loop init
    }
    __syncthreads();
    int wid = t >> 6, lane = t & 63;
    int ecount = eend - estart;
    int emain = ecount & ~31;
    for (int i = estart + wid * 8; i < estart + emain; i += 32) {
        int idx = ebuf2[i + (lane & 7)];
        int s0 = __shfl(idx, 0), s1 = __shfl(idx, 1);
        int s2 = __shfl(idx, 2), s3 = __shfl(idx, 3);
        int s4 = __shfl(idx, 4), s5 = __shfl(idx, 5);
        int s6 = __shfl(idx, 6), s7 = __shfl(idx, 7);
        float v0 = h1s[(size_t)(((unsigned)s0) >> BSHIFT) * 64 + lane];
        float v1 = h1s[(size_t)(((unsigned)s1) >> BSHIFT) * 64 + lane];
        float v2 = h1s[(size_t)(((unsigned)s2) >> BSHIFT) * 64 + lane];
        float v3 = h1s[(size_t)(((unsigned)s3) >> BSHIFT) * 64 + lane];
        float v4 = h1s[(size_t)(((unsigned)s4) >> BSHIFT) * 64 + lane];
        float v5 = h1s[(size_t)(((unsigned)s5) >> BSHIFT) * 64 + lane];
        float v6 = h1s[(size_t)(((unsigned)s6) >> BSHIFT) * 64 + lane];
        float v7 = h1s[(size_t)(((unsigned)s7) >> BSHIFT) * 64 + lane];
        atomicAdd(&accA[(s0 & (BSIZE - 1)) * STA + lane], v0);
        atomicAdd(&accA[(s1 & (BSIZE - 1)) * STA + lane], v1);
        atomicAdd(&accA[(s2 & (BSIZE - 1)) * STA + lane], v2);
        atomicAdd(&accA[(s3 & (BSIZE - 1)) * STA + lane], v3);
        atomicAdd(&accA[(s4 & (BSIZE - 1)) * STA + lane], v4);
        atomicAdd(&accA[(s5 & (BSIZE - 1)) * STA + lane], v5);
        atomicAdd(&accA[(s6 & (BSIZE - 1)) * STA + lane], v6);
        atomicAdd(&accA[(s7 & (BSIZE - 1)) * STA + lane], v7);
    }
    for (int i = estart + emain + wid; i < eend; i += 4) {   // tail < 32
        int w = ebuf2[i];
        float v = h1s[(size_t)(((unsigned)w) >> BSHIFT) * 64 + lane];
        atomicAdd(&accA[(w & (BSIZE - 1)) * STA + lane], v);
    }
    __syncthreads();
    // h1r = relu(dis*acc + b1), in place
    for (int idx = t; idx < 2048; idx += 256) {
        int row = idx >> 4, q = idx & 15;
        float d = disS[row];
        float4 v = *(float4*)&accA[row * STA + q * 4];
        float4 bq = *(float4*)&b1S[q * 4];
        v.x = fmaxf(fmaf(d, v.x, bq.x), 0.f);
        v.y = fmaxf(fmaf(d, v.y, bq.y), 0.f);
        v.z = fmaxf(fmaf(d, v.z, bq.z), 0.f);
        v.w = fmaxf(fmaf(d, v.w, bq.w), 0.f);
        *(float4*)&accA[row * STA + q * 4] = v;
    }
    __syncthreads();
    // gemm2: thread = (rg 0..31, cg 0..7); 4 rows x 4 cols each
    int rg = t >> 3, cg = t & 7;
    int row0 = rg * 4, col0 = cg * 4;
    float4 c0 = {0.f,0.f,0.f,0.f}, c1 = c0, c2 = c0, c3 = c0;
#pragma unroll 4
    for (int k4 = 0; k4 < 16; ++k4) {
        int kk = k4 * 4;
        float4 a0 = *(const float4*)&accA[(row0 + 0) * STA + kk];
        float4 a1 = *(const float4*)&accA[(row0 + 1) * STA + kk];
        float4 a2 = *(const float4*)&accA[(row0 + 2) * STA + kk];
        float4 a3 = *(const float4*)&accA[(row0 + 3) * STA + kk];
        float4 w0 = *(const float4*)&Ws[(kk + 0) * 32 + col0];
        float4 w1 = *(const float4*)&Ws[(kk + 1) * 32 + col0];
        float4 w2 = *(const float4*)&Ws[(kk + 2) * 32 + col0];
        float4 w3 = *(const float4*)&Ws[(kk + 3) * 32 + col0];
        f4fma(c0, a0.x, w0); f4fma(c0, a0.y, w1); f4fma(c0, a0.z, w2); f4fma(c0, a0.w, w3);
        f4fma(c1, a1.x, w0); f4fma(c1, a1.y, w1); f4fma(c1, a1.z, w2); f4fma(c1, a1.w, w3);
        f4fma(c2, a2.x, w0); f4fma(c2, a2.y, w1); f4fma(c2, a2.z, w2); f4fma(c2, a2.w, w3);
        f4fma(c3, a3.x, w0); f4fma(c3, a3.y, w1); f4fma(c3, a3.z, w2); f4fma(c3, a3.w, w3);
    }
#pragma unroll
    for (int r = 0; r < 4; ++r) {
        int node = nb + row0 + r;
        if (node < n) {
            float d = disS[row0 + r];
            float4 o = (r == 0) ? c0 : (r == 1) ? c1 : (r == 2) ? c2 : c3;
            o.x *= d; o.y *= d; o.z *= d; o.w *= d;
            *(float4*)&h2s[(size_t)node * 32 + col0] = o;
        }
    }
}

// layer-2 aggregation (LDS acc, src-sorted, 8 edges/wave-iter via 2 halves
// x 4 unroll) fused with relu+b2 and FC head.
__global__ __launch_bounds__(256) void k_agg2f(
        const float* __restrict__ h2s, const int* __restrict__ ebuf2,
        const int* __restrict__ ghist_s, const float* __restrict__ dis,
        const float* __restrict__ b2, const float* __restrict__ Wfc,
        const float* __restrict__ bfc, float* __restrict__ out,
        int n, int e, int nbuck) {
    __shared__ float accB[BSIZE * STB];   // 18432 B
    __shared__ float disS[BSIZE];
    int k = blockIdx.x, t = threadIdx.x;
    int estart = ghist_s[k * B1];
    int eend = (k + 1 < nbuck) ? ghist_s[(k + 1) * B1] : e;
    int nb = k * BSIZE;
    if (t < BSIZE) disS[t] = dis[min(nb + t, n - 1)];
    for (int i = t; i < 1024; i += 256) {
        int row = i >> 3, q = i & 7;
        int node = nb + row; if (node >= n) node = n - 1;
        float4 v = ((const float4*)(h2s + (size_t)node * 32))[q];
        *(float4*)&accB[row * STB + q * 4] = v;      // self-loop init
    }
    __syncthreads();
    int wid = t >> 6, lane = t & 63;
    int f = lane & 31, h = lane >> 5;
    int ecount = eend - estart;
    int emain = ecount & ~31;
    for (int i = estart + wid * 8; i < estart + emain; i += 32) {
        int idx = ebuf2[i + (lane & 7)];
        int s0 = __shfl(idx, h);
        int s1 = __shfl(idx, h + 2);
        int s2 = __shfl(idx, h + 4);
        int s3 = __shfl(idx, h + 6);
        float v0 = h2s[(size_t)(((unsigned)s0) >> BSHIFT) * 32 + f];
        float v1 = h2s[(size_t)(((unsigned)s1) >> BSHIFT) * 32 + f];
        float v2 = h2s[(size_t)(((unsigned)s2) >> BSHIFT) * 32 + f];
        float v3 = h2s[(size_t)(((unsigned)s3) >> BSHIFT) * 32 + f];
        atomicAdd(&accB[(s0 & (BSIZE - 1)) * STB + f], v0);
        atomicAdd(&accB[(s1 & (BSIZE - 1)) * STB + f], v1);
        atomicAdd(&accB[(s2 & (BSIZE - 1)) * STB + f], v2);
        atomicAdd(&accB[(s3 & (BSIZE - 1)) * STB + f], v3);
    }
    for (int i = estart + emain + wid * 2 + h; i < eend; i += 8) {  // tail
        int w = ebuf2[i];
        float v = h2s[(size_t)(((unsigned)w) >> BSHIFT) * 32 + f];
        atomicAdd(&accB[(w & (BSIZE - 1)) * STB + f], v);
    }
    __syncthreads();
    float wf = Wfc[f];
    float b2f = b2[f];
    float bf = bfc[0];
    for (int row = wid * 2 + h; row < BSIZE; row += 8) {
        int node = nb + row;
        float v = accB[row * STB + f];
        float val = fmaxf(fmaf(disS[row], v, b2f), 0.f) * wf;
        val += __shfl_xor(val, 1);  val += __shfl_xor(val, 2);
        val += __shfl_xor(val, 4);  val += __shfl_xor(val, 8);
        val += __shfl_xor(val, 16);
        if (f == 0 && node < n) out[node] = val + bf;
    }
}

extern "C" void kernel_launch(void* const* d_in, const int* in_sizes, int n_in,
                              void* d_out, int out_size, void* d_ws, size_t ws_size,
                              hipStream_t stream) {
    const float* x   = (const float*)d_in[0];
    const int*   ei  = (const int*)d_in[1];
    const float* W1  = (const float*)d_in[2];
    const float* b1  = (const float*)d_in[3];
    const float* W2  = (const float*)d_in[4];
    const float* b2  = (const float*)d_in[5];
    const float* Wfc = (const float*)d_in[6];
    const float* bfc = (const float*)d_in[7];
    float* out = (float*)d_out;

    const int n = in_sizes[0] / 128;       // 100000
    const int e = in_sizes[1] / 2;         // 3200000
    const int* src = ei;
    const int* dst = ei + e;

    const int nbuck = (n + BSIZE - 1) / BSIZE;           // 782
    const int m = nbuck * B1;                            // 200192
    const int echunk = (e + B1 - 1) / B1;                // 12500
    int sshift = 9;                                      // src bins <= 256
    while (((n - 1) >> sshift) >= 256) ++sshift;

    char* p = (char*)d_ws;
    size_t off = 0;
    auto carve = [&](size_t bytes) { void* r = p + off; off = (off + bytes + 255) & ~(size_t)255; return r; };
    int*   ghist   = (int*)  carve((size_t)m * 4);
    int*   ghist_s = (int*)  carve((size_t)m * 4);
    int*   part    = (int*)  carve(256 * 4);
    float* dis     = (float*)carve((size_t)n * 4);
    int*   ebuf2   = (int*)  carve((size_t)e * 4);
    float* h2s     = (float*)carve((size_t)n * 32 * 4);
    void*  ebuf_or_h1s = carve((size_t)n * 64 * 4);      // ebuf(E*4) aliases h1s
    int*   ebuf = (int*)ebuf_or_h1s;
    float* h1s  = (float*)ebuf_or_h1s;
    (void)ws_size;

    const int nblk_scan = (m + SCAN_CHUNK - 1) / SCAN_CHUNK;   // 196 (<=256)
    const size_t lds_buck = (size_t)nbuck * 4;

    k_hist<<<B1, 256, lds_buck, stream>>>(dst, ghist, e, echunk, nbuck);
    k_gscan1<<<nblk_scan, 256, 0, stream>>>(ghist, part, m);
    k_gscan2<<<nblk_scan, 256, 0, stream>>>(ghist, part, ghist_s, m, nblk_scan);
    k_binscatter<<<B1, 256, lds_buck, stream>>>(src, dst, ghist_s, ebuf, e, echunk, nbuck);
    k_sort<<<nbuck, 256, 0, stream>>>(ebuf, ghist_s, ebuf2, dis, n, e, nbuck, sshift);
    k_gemm1<<<(n + 63) / 64, 256, 0, stream>>>(x, W1, dis, h1s, n);
    k_agg1f<<<nbuck, 256, 0, stream>>>(h1s, ebuf2, ghist_s, dis, b1, W2, h2s, n, e, nbuck);
    k_agg2f<<<nbuck, 256, 0, stream>>>(h2s, ebuf2, ghist_s, dis, b2, Wfc, bfc, out, n, e, nbuck);
}

// Round 9
// 607.330 us; speedup vs baseline: 3.8750x; 3.8750x over previous
//
#include <hip/hip_runtime.h>
#include <hip/hip_bf16.h>

// GCN: h = relu(GCN(x,W1,b1)); h = relu(GCN(h,W2,b2)); out = h @ Wfc + bfc
// GCN(x,W,b)[d] = dis[d] * ( sum_{(s,d) in E} hs[s] + hs[d] ) + b
//   where hs[v] = (x[v]@W) * dis[v],  dis[v] = rsqrt(1 + indeg(v))
//
// Round-9 structure: binned counting sort -> per-bucket DST-sorted edge list
// (bucket-local CSR).  k_agg1f: wave-chunk run-accumulation in registers,
// one LDS += per dst-run (atomic only at chunk boundaries) -- kills the
// round-7/8 per-edge LDS fp-atomic serialization.  gemm2 fused into agg1f
// epilogue (no h1r in HBM); agg2 = round-6 proven multi-edge gather + FC.

#define SCAN_CHUNK 1024
#define BSHIFT 7
#define BSIZE 128            // dsts per bucket
#define B1 256               // blocks in hist/binscatter passes
#define STA 68               // acc stride for 64-f rows (float4-aligned)

__device__ inline void f4fma(float4& a, float s, const float4& b) {
    a.x = fmaf(s, b.x, a.x); a.y = fmaf(s, b.y, a.y);
    a.z = fmaf(s, b.z, a.z); a.w = fmaf(s, b.w, a.w);
}
__device__ inline void f4add(float4& a, const float4& b) {
    a.x += b.x; a.y += b.y; a.z += b.z; a.w += b.w;
}
__device__ inline void f4red(float4& a, int off) {
    a.x += __shfl_xor(a.x, off); a.y += __shfl_xor(a.y, off);
    a.z += __shfl_xor(a.z, off); a.w += __shfl_xor(a.w, off);
}

// ---- generic exclusive scan (m ints, nblk = ceil(m/1024) <= 256) ----
__global__ void k_gscan1(const int* __restrict__ in, int* __restrict__ part, int m) {
    int t = threadIdx.x;
    int base = blockIdx.x * SCAN_CHUNK + t * 4;
    int s = 0;
    for (int u = 0; u < 4; ++u) { int i = base + u; if (i < m) s += in[i]; }
    for (int o = 32; o; o >>= 1) s += __shfl_down(s, o);
    __shared__ int ws[4];
    if ((t & 63) == 0) ws[t >> 6] = s;
    __syncthreads();
    if (t == 0) part[blockIdx.x] = ws[0] + ws[1] + ws[2] + ws[3];
}

__global__ void k_gscan2(const int* __restrict__ in, const int* __restrict__ part,
                         int* __restrict__ out, int m, int nblk) {
    int t = threadIdx.x;
    int b = blockIdx.x;
    int pv = (t < b && t < nblk) ? part[t] : 0;
    int ps = pv;
    for (int o = 32; o; o >>= 1) ps += __shfl_down(ps, o);
    __shared__ int sh[4];
    if ((t & 63) == 0) sh[t >> 6] = ps;
    __syncthreads();
    int blockoff = sh[0] + sh[1] + sh[2] + sh[3];

    int base = b * SCAN_CHUNK + t * 4;
    int v0 = 0, v1 = 0, v2 = 0, v3 = 0;
    if (base + 0 < m) v0 = in[base + 0];
    if (base + 1 < m) v1 = in[base + 1];
    if (base + 2 < m) v2 = in[base + 2];
    if (base + 3 < m) v3 = in[base + 3];
    int tot = v0 + v1 + v2 + v3;
    int lane = t & 63, wid = t >> 6;
    int incl = tot;
    for (int o = 1; o < 64; o <<= 1) { int u = __shfl_up(incl, o); if (lane >= o) incl += u; }
    int excl = incl - tot;
    __shared__ int wt[4];
    if (lane == 63) wt[wid] = incl;
    __syncthreads();
    int woff = 0;
    for (int w = 0; w < wid; ++w) woff += wt[w];
    int off = blockoff + woff + excl;
    if (base + 0 < m) out[base + 0] = off;
    if (base + 1 < m) out[base + 1] = off + v0;
    if (base + 2 < m) out[base + 2] = off + v0 + v1;
    if (base + 3 < m) out[base + 3] = off + v0 + v1 + v2;
}

// ---- pass 1a: per-block bucket histogram (LDS atomics only) ----
__global__ __launch_bounds__(256) void k_hist(const int* __restrict__ dst,
                                              int* __restrict__ ghist,
                                              int e, int echunk, int nbuck) {
    extern __shared__ int h[];   // nbuck ints
    int t = threadIdx.x, b = blockIdx.x;
    for (int i = t; i < nbuck; i += 256) h[i] = 0;
    __syncthreads();
    int s = b * echunk, epd = min(e, s + echunk);
    for (int i = s + t; i < epd; i += 256)
        atomicAdd(&h[dst[i] >> BSHIFT], 1);
    __syncthreads();
    for (int k = t; k < nbuck; k += 256)
        ghist[k * B1 + b] = h[k];
}

// ---- pass 1b: scatter packed (src<<7|dlow) into bucket-ordered ebuf ----
__global__ __launch_bounds__(256) void k_binscatter(
        const int* __restrict__ src, const int* __restrict__ dst,
        const int* __restrict__ ghist_s, int* __restrict__ ebuf,
        int e, int echunk, int nbuck) {
    extern __shared__ int cur[];   // nbuck ints
    int t = threadIdx.x, b = blockIdx.x;
    for (int k = t; k < nbuck; k += 256)
        cur[k] = ghist_s[k * B1 + b];
    __syncthreads();
    int s = b * echunk, epd = min(e, s + echunk);
    for (int i = s + t; i < epd; i += 256) {
        int d = dst[i];
        int pos = atomicAdd(&cur[d >> BSHIFT], 1);
        ebuf[pos] = (src[i] << BSHIFT) | (d & (BSIZE - 1));
    }
}

// ---- pass 2: per-bucket dst counting sort -> ebuf2 (bucket-local CSR) ----
// Also emits rowptr/degi/dis.
__global__ __launch_bounds__(256) void k_csr(
        const int* __restrict__ ebuf, const int* __restrict__ ghist_s,
        int* __restrict__ ebuf2, int* __restrict__ rowptr, int* __restrict__ degi,
        float* __restrict__ dis, int n, int e, int nbuck) {
    int k = blockIdx.x, t = threadIdx.x;
    int estart = ghist_s[k * B1];
    int eend = (k + 1 < nbuck) ? ghist_s[(k + 1) * B1] : e;
    __shared__ int cnt[BSIZE];
    __shared__ int cur[BSIZE];
    __shared__ int wt[4];
    if (t < BSIZE) cnt[t] = 0;
    __syncthreads();
    for (int i = estart + t; i < eend; i += 256)
        atomicAdd(&cnt[ebuf[i] & (BSIZE - 1)], 1);
    __syncthreads();
    int v = (t < BSIZE) ? cnt[t] : 0;
    int lane = t & 63, wid = t >> 6;
    int incl = v;
    for (int o = 1; o < 64; o <<= 1) { int u = __shfl_up(incl, o); if (lane >= o) incl += u; }
    if (lane == 63) wt[wid] = incl;
    __syncthreads();
    int woff = (wid == 1) ? wt[0] : 0;
    int excl = woff + incl - v;
    if (t < BSIZE) {
        cur[t] = estart + excl;
        int node = k * BSIZE + t;
        if (node < n) {
            rowptr[node] = estart + excl;
            degi[node]   = v;
            dis[node]    = rsqrtf((float)(v + 1));
        }
    }
    __syncthreads();
    for (int i = estart + t; i < eend; i += 256) {
        int w = ebuf[i];
        int pos = atomicAdd(&cur[w & (BSIZE - 1)], 1);
        ebuf2[pos] = w;      // keep packed (src<<7 | dlow), now dst-sorted
    }
}

// h1s = (x @ W1) * dis — outer-product GEMM, block tile 64x64, K=128.
#define SA 132
__global__ __launch_bounds__(256) void k_gemm1(
        const float* __restrict__ x, const float* __restrict__ W1,
        const float* __restrict__ dis, float* __restrict__ h1s, int n) {
    __shared__ float Xs[64 * SA];    // 33 KB
    __shared__ float Ws[128 * 64];   // 32 KB
    int t = threadIdx.x;
    int nbase = blockIdx.x * 64;
    for (int i = t; i < 2048; i += 256)
        ((float4*)Ws)[i] = ((const float4*)W1)[i];
    for (int i = t; i < 2048; i += 256) {
        int row = i >> 5, q = i & 31;
        int r = nbase + row; if (r >= n) r = n - 1;
        float4 v = ((const float4*)(x + (size_t)r * 128))[q];
        *(float4*)&Xs[row * SA + q * 4] = v;
    }
    __syncthreads();
    int wid = t >> 6, lane = t & 63;
    int lx = lane & 7, ly = lane >> 3;
    int wm = wid & 1, wn = wid >> 1;
    int row0 = wm * 32 + ly * 4;
    int col0 = wn * 32 + lx * 4;
    float4 acc0 = {0.f,0.f,0.f,0.f}, acc1 = acc0, acc2 = acc0, acc3 = acc0;
#pragma unroll 4
    for (int k4 = 0; k4 < 32; ++k4) {
        int k = k4 * 4;
        float4 a0 = *(const float4*)&Xs[(row0 + 0) * SA + k];
        float4 a1 = *(const float4*)&Xs[(row0 + 1) * SA + k];
        float4 a2 = *(const float4*)&Xs[(row0 + 2) * SA + k];
        float4 a3 = *(const float4*)&Xs[(row0 + 3) * SA + k];
        float4 b0 = *(const float4*)&Ws[(k + 0) * 64 + col0];
        float4 b1 = *(const float4*)&Ws[(k + 1) * 64 + col0];
        float4 b2 = *(const float4*)&Ws[(k + 2) * 64 + col0];
        float4 b3 = *(const float4*)&Ws[(k + 3) * 64 + col0];
        f4fma(acc0, a0.x, b0); f4fma(acc0, a0.y, b1); f4fma(acc0, a0.z, b2); f4fma(acc0, a0.w, b3);
        f4fma(acc1, a1.x, b0); f4fma(acc1, a1.y, b1); f4fma(acc1, a1.z, b2); f4fma(acc1, a1.w, b3);
        f4fma(acc2, a2.x, b0); f4fma(acc2, a2.y, b1); f4fma(acc2, a2.z, b2); f4fma(acc2, a2.w, b3);
        f4fma(acc3, a3.x, b0); f4fma(acc3, a3.y, b1); f4fma(acc3, a3.z, b2); f4fma(acc3, a3.w, b3);
    }
    int grow = nbase + row0;
#pragma unroll
    for (int r = 0; r < 4; ++r) {
        int rr = grow + r;
        if (rr < n) {
            float d = dis[rr];
            float4 o = (r == 0) ? acc0 : (r == 1) ? acc1 : (r == 2) ? acc2 : acc3;
            o.x *= d; o.y *= d; o.z *= d; o.w *= d;
            *(float4*)&h1s[(size_t)rr * 64 + col0] = o;
        }
    }
}

// layer-1 aggregation: block = bucket; wave = contiguous chunk of the
// bucket's dst-sorted edges; same-dst runs accumulate in a register and
// flush ONCE to LDS (plain += interior, atomic at chunk boundaries).
// Epilogue: relu(dis*acc+b1) then fused gemm2 -> h2s.
__global__ __launch_bounds__(256) void k_agg1f(
        const float* __restrict__ h1s, const int* __restrict__ ebuf2,
        const int* __restrict__ ghist_s, const float* __restrict__ dis,
        const float* __restrict__ b1, const float* __restrict__ W2,
        float* __restrict__ h2s, int n, int e, int nbuck) {
    __shared__ float accA[BSIZE * STA];   // 34816 B
    __shared__ float Ws[64 * 32];         // 8 KB
    __shared__ float disS[BSIZE];
    __shared__ float b1S[64];
    int k = blockIdx.x, t = threadIdx.x;
    int estart = ghist_s[k * B1];
    int eend = (k + 1 < nbuck) ? ghist_s[(k + 1) * B1] : e;
    int nb = k * BSIZE;
    for (int i = t; i < 512; i += 256)
        ((float4*)Ws)[i] = ((const float4*)W2)[i];
    if (t < 64) b1S[t] = b1[t];
    if (t < BSIZE) disS[t] = dis[min(nb + t, n - 1)];
    for (int i = t; i < 2048; i += 256) {
        int row = i >> 4, q = i & 15;
        int node = nb + row; if (node >= n) node = n - 1;
        float4 v = ((const float4*)(h1s + (size_t)node * 64))[q];
        *(float4*)&accA[row * STA + q * 4] = v;      // self-loop init
    }
    __syncthreads();
    int wid = t >> 6, lane = t & 63;
    int ecount = eend - estart;
    int chunk = (ecount + 3) >> 2;
    int cs = estart + wid * chunk;
    int ce = min(cs + chunk, eend);
    if (cs < ce) {
        float acc = 0.f;
        int curd = -1;
        bool firstRun = true;
        for (int ibase = cs; ibase < ce; ibase += 64) {
            int idx = ebuf2[min(ibase + lane, eend - 1)];
            int gn = min(64, ce - ibase);
            for (int j = 0; j < gn; j += 4) {
                int j1 = min(j + 1, gn - 1), j2 = min(j + 2, gn - 1), j3 = min(j + 3, gn - 1);
                int w0 = __shfl(idx, j),  w1 = __shfl(idx, j1);
                int w2 = __shfl(idx, j2), w3 = __shfl(idx, j3);
                // 4 independent row loads (MLP 4)
                float v0 = h1s[(size_t)(((unsigned)w0) >> BSHIFT) * 64 + lane];
                float v1 = h1s[(size_t)(((unsigned)w1) >> BSHIFT) * 64 + lane];
                float v2 = h1s[(size_t)(((unsigned)w2) >> BSHIFT) * 64 + lane];
                float v3 = h1s[(size_t)(((unsigned)w3) >> BSHIFT) * 64 + lane];
                int d0 = w0 & (BSIZE - 1), d1 = w1 & (BSIZE - 1);
                int d2 = w2 & (BSIZE - 1), d3 = w3 & (BSIZE - 1);
                // fold (dst is wave-uniform -> uniform branches)
                if (d0 != curd) {
                    if (curd >= 0) {
                        if (firstRun) { atomicAdd(&accA[curd * STA + lane], acc); firstRun = false; }
                        else accA[curd * STA + lane] += acc;
                    }
                    curd = d0; acc = 0.f;
                }
                acc += v0;
                if (j + 1 < gn) {
                    if (d1 != curd) {
                        if (firstRun) { atomicAdd(&accA[curd * STA + lane], acc); firstRun = false; }
                        else accA[curd * STA + lane] += acc;
                        curd = d1; acc = 0.f;
                    }
                    acc += v1;
                }
                if (j + 2 < gn) {
                    if (d2 != curd) {
                        if (firstRun) { atomicAdd(&accA[curd * STA + lane], acc); firstRun = false; }
                        else accA[curd * STA + lane] += acc;
                        curd = d2; acc = 0.f;
                    }
                    acc += v2;
                }
                if (j + 3 < gn) {
                    if (d3 != curd) {
                        if (firstRun) { atomicAdd(&accA[curd * STA + lane], acc); firstRun = false; }
                        else accA[curd * STA + lane] += acc;
                        curd = d3; acc = 0.f;
                    }
                    acc += v3;
                }
            }
        }
        if (curd >= 0) atomicAdd(&accA[curd * STA + lane], acc);  // last run: may span chunks
    }
    __syncthreads();
    // h1r = relu(dis*acc + b1), in place
    for (int idx = t; idx < 2048; idx += 256) {
        int row = idx >> 4, q = idx & 15;
        float d = disS[row];
        float4 v = *(float4*)&accA[row * STA + q * 4];
        float4 bq = *(float4*)&b1S[q * 4];
        v.x = fmaxf(fmaf(d, v.x, bq.x), 0.f);
        v.y = fmaxf(fmaf(d, v.y, bq.y), 0.f);
        v.z = fmaxf(fmaf(d, v.z, bq.z), 0.f);
        v.w = fmaxf(fmaf(d, v.w, bq.w), 0.f);
        *(float4*)&accA[row * STA + q * 4] = v;
    }
    __syncthreads();
    // gemm2: thread = (rg 0..31, cg 0..7); 4 rows x 4 cols each
    int rg = t >> 3, cg = t & 7;
    int row0 = rg * 4, col0 = cg * 4;
    float4 c0 = {0.f,0.f,0.f,0.f}, c1 = c0, c2 = c0, c3 = c0;
#pragma unroll 4
    for (int k4 = 0; k4 < 16; ++k4) {
        int kk = k4 * 4;
        float4 a0 = *(const float4*)&accA[(row0 + 0) * STA + kk];
        float4 a1 = *(const float4*)&accA[(row0 + 1) * STA + kk];
        float4 a2 = *(const float4*)&accA[(row0 + 2) * STA + kk];
        float4 a3 = *(const float4*)&accA[(row0 + 3) * STA + kk];
        float4 w0 = *(const float4*)&Ws[(kk + 0) * 32 + col0];
        float4 w1 = *(const float4*)&Ws[(kk + 1) * 32 + col0];
        float4 w2 = *(const float4*)&Ws[(kk + 2) * 32 + col0];
        float4 w3 = *(const float4*)&Ws[(kk + 3) * 32 + col0];
        f4fma(c0, a0.x, w0); f4fma(c0, a0.y, w1); f4fma(c0, a0.z, w2); f4fma(c0, a0.w, w3);
        f4fma(c1, a1.x, w0); f4fma(c1, a1.y, w1); f4fma(c1, a1.z, w2); f4fma(c1, a1.w, w3);
        f4fma(c2, a2.x, w0); f4fma(c2, a2.y, w1); f4fma(c2, a2.z, w2); f4fma(c2, a2.w, w3);
        f4fma(c3, a3.x, w0); f4fma(c3, a3.y, w1); f4fma(c3, a3.z, w2); f4fma(c3, a3.w, w3);
    }
#pragma unroll
    for (int r = 0; r < 4; ++r) {
        int node = nb + row0 + r;
        if (node < n) {
            float d = disS[row0 + r];
            float4 o = (r == 0) ? c0 : (r == 1) ? c1 : (r == 2) ? c2 : c3;
            o.x *= d; o.y *= d; o.z *= d; o.w *= d;
            *(float4*)&h2s[(size_t)node * 32 + col0] = o;
        }
    }
}

// layer-2 aggregation + relu + FC head (round-6 proven structure).
// wave per dst; eg = lane>>3 (8 edge slots), fq = (lane&7)*4.
// One dwordx4 gather covers 8 edges x 128 B; entries are packed (src = w>>7).
__global__ void k_agg2(const float* __restrict__ h2s, const int* __restrict__ ents,
                       const int* __restrict__ rowptr, const int* __restrict__ degi,
                       const float* __restrict__ dis, const float* __restrict__ b2,
                       const float* __restrict__ Wfc, const float* __restrict__ bfc,
                       float* __restrict__ out, int n) {
    int wid = threadIdx.x >> 6, lane = threadIdx.x & 63;
    int v = blockIdx.x * 4 + wid;
    if (v >= n) return;
    int start = rowptr[v], cnt = degi[v];
    int eg = lane >> 3;
    int fq = (lane & 7) * 4;
    float4 acc = {0.f, 0.f, 0.f, 0.f};
    if (cnt > 0 && cnt <= 64) {
        int pre = ents[start + min(lane, cnt - 1)];
        int ng = cnt >> 3;
#pragma unroll 4
        for (int g = 0; g < ng; ++g) {
            unsigned s = ((unsigned)__shfl(pre, g * 8 + eg)) >> BSHIFT;
            f4add(acc, *(const float4*)&h2s[(size_t)s * 32 + fq]);
        }
        int rem = cnt & 7, j0 = cnt & ~7;
        if (rem) {
            unsigned s = ((unsigned)__shfl(pre, j0 + (eg < rem ? eg : 0))) >> BSHIFT;
            float4 a = *(const float4*)&h2s[(size_t)s * 32 + fq];
            if (eg < rem) f4add(acc, a);
        }
    } else if (cnt > 64) {
        int j = 0;
        for (; j + 8 <= cnt; j += 8) {
            unsigned s = ((unsigned)ents[start + j + eg]) >> BSHIFT;
            f4add(acc, *(const float4*)&h2s[(size_t)s * 32 + fq]);
        }
        int rem = cnt - j;
        if (rem) {
            unsigned s = ((unsigned)ents[start + j + (eg < rem ? eg : 0)]) >> BSHIFT;
            float4 a = *(const float4*)&h2s[(size_t)s * 32 + fq];
            if (eg < rem) f4add(acc, a);
        }
    }
    if (eg == 0) f4add(acc, *(const float4*)&h2s[(size_t)v * 32 + fq]);  // self
    f4red(acc, 8); f4red(acc, 16); f4red(acc, 32);
    float p = 0.f;
    if (eg == 0) {
        float d = dis[v];
        float4 bq = *(const float4*)&b2[fq];
        float4 wq = *(const float4*)&Wfc[fq];
        p  = fmaxf(fmaf(d, acc.x, bq.x), 0.f) * wq.x;
        p += fmaxf(fmaf(d, acc.y, bq.y), 0.f) * wq.y;
        p += fmaxf(fmaf(d, acc.z, bq.z), 0.f) * wq.z;
        p += fmaxf(fmaf(d, acc.w, bq.w), 0.f) * wq.w;
    }
    p += __shfl_xor(p, 1); p += __shfl_xor(p, 2); p += __shfl_xor(p, 4);
    if (lane == 0) out[v] = p + bfc[0];
}

extern "C" void kernel_launch(void* const* d_in, const int* in_sizes, int n_in,
                              void* d_out, int out_size, void* d_ws, size_t ws_size,
                              hipStream_t stream) {
    const float* x   = (const float*)d_in[0];
    const int*   ei  = (const int*)d_in[1];
    const float* W1  = (const float*)d_in[2];
    const float* b1  = (const float*)d_in[3];
    const float* W2  = (const float*)d_in[4];
    const float* b2  = (const float*)d_in[5];
    const float* Wfc = (const float*)d_in[6];
    const float* bfc = (const float*)d_in[7];
    float* out = (float*)d_out;

    const int n = in_sizes[0] / 128;       // 100000
    const int e = in_sizes[1] / 2;         // 3200000
    const int* src = ei;
    const int* dst = ei + e;

    const int nbuck = (n + BSIZE - 1) / BSIZE;           // 782
    const int m = nbuck * B1;                            // 200192
    const int echunk = (e + B1 - 1) / B1;                // 12500

    char* p = (char*)d_ws;
    size_t off = 0;
    auto carve = [&](size_t bytes) { void* r = p + off; off = (off + bytes + 255) & ~(size_t)255; return r; };
    int*   ghist   = (int*)  carve((size_t)m * 4);
    int*   ghist_s = (int*)  carve((size_t)m * 4);
    int*   part    = (int*)  carve(256 * 4);
    float* dis     = (float*)carve((size_t)n * 4);
    int*   rowptr  = (int*)  carve((size_t)n * 4);
    int*   degi    = (int*)  carve((size_t)n * 4);
    int*   ebuf2   = (int*)  carve((size_t)e * 4);
    float* h2s     = (float*)carve((size_t)n * 32 * 4);
    void*  ebuf_or_h1s = carve((size_t)n * 64 * 4);      // ebuf(E*4) aliases h1s
    int*   ebuf = (int*)ebuf_or_h1s;
    float* h1s  = (float*)ebuf_or_h1s;
    (void)ws_size;

    const int nblk_scan = (m + SCAN_CHUNK - 1) / SCAN_CHUNK;   // 196 (<=256)
    const size_t lds_buck = (size_t)nbuck * 4;

    k_hist<<<B1, 256, lds_buck, stream>>>(dst, ghist, e, echunk, nbuck);
    k_gscan1<<<nblk_scan, 256, 0, stream>>>(ghist, part, m);
    k_gscan2<<<nblk_scan, 256, 0, stream>>>(ghist, part, ghist_s, m, nblk_scan);
    k_binscatter<<<B1, 256, lds_buck, stream>>>(src, dst, ghist_s, ebuf, e, echunk, nbuck);
    k_csr<<<nbuck, 256, 0, stream>>>(ebuf, ghist_s, ebuf2, rowptr, degi, dis, n, e, nbuck);
    k_gemm1<<<(n + 63) / 64, 256, 0, stream>>>(x, W1, dis, h1s, n);
    k_agg1f<<<nbuck, 256, 0, stream>>>(h1s, ebuf2, ghist_s, dis, b1, W2, h2s, n, e, nbuck);
    k_agg2<<<(n + 3) / 4, 256, 0, stream>>>(h2s, ebuf2, rowptr, degi, dis, b2, Wfc, bfc, out, n);
}

// Round 10
// 383.344 us; speedup vs baseline: 6.1392x; 1.5843x over previous
//
#include <hip/hip_runtime.h>
#include <hip/hip_bf16.h>

// GCN: h = relu(GCN(x,W1,b1)); h = relu(GCN(h,W2,b2)); out = h @ Wfc + bfc
// GCN(x,W,b)[d] = dis[d] * ( sum_{(s,d) in E} hs[s] + hs[d] ) + b
//   where hs[v] = (x[v]@W) * dis[v],  dis[v] = rsqrt(1 + indeg(v))
//
// Round-10: binned counting sort -> packed dst-sorted CSR (ebuf2, src=w>>7).
// Layer-1 = round-6 proven multi-edge dwordx4 gather (wave per dst, 4 edges
// per vmem inst) + IN-WAVE fused relu/b1 + gemm2 (W2 column in registers,
// h1r row via tiny LDS) -> writes h2s directly.  h1r / k_gemm2 eliminated.
// Layer-2 = round-6 multi-edge gather + fused relu/b2/FC.

#define SCAN_CHUNK 1024
#define BSHIFT 7
#define BSIZE 128            // dsts per bucket
#define B1 256               // blocks in hist/binscatter passes

__device__ inline void f4fma(float4& a, float s, const float4& b) {
    a.x = fmaf(s, b.x, a.x); a.y = fmaf(s, b.y, a.y);
    a.z = fmaf(s, b.z, a.z); a.w = fmaf(s, b.w, a.w);
}
__device__ inline void f4add(float4& a, const float4& b) {
    a.x += b.x; a.y += b.y; a.z += b.z; a.w += b.w;
}
__device__ inline void f4red(float4& a, int off) {
    a.x += __shfl_xor(a.x, off); a.y += __shfl_xor(a.y, off);
    a.z += __shfl_xor(a.z, off); a.w += __shfl_xor(a.w, off);
}

// ---- generic exclusive scan (m ints, nblk = ceil(m/1024) <= 256) ----
__global__ void k_gscan1(const int* __restrict__ in, int* __restrict__ part, int m) {
    int t = threadIdx.x;
    int base = blockIdx.x * SCAN_CHUNK + t * 4;
    int s = 0;
    for (int u = 0; u < 4; ++u) { int i = base + u; if (i < m) s += in[i]; }
    for (int o = 32; o; o >>= 1) s += __shfl_down(s, o);
    __shared__ int ws[4];
    if ((t & 63) == 0) ws[t >> 6] = s;
    __syncthreads();
    if (t == 0) part[blockIdx.x] = ws[0] + ws[1] + ws[2] + ws[3];
}

__global__ void k_gscan2(const int* __restrict__ in, const int* __restrict__ part,
                         int* __restrict__ out, int m, int nblk) {
    int t = threadIdx.x;
    int b = blockIdx.x;
    int pv = (t < b && t < nblk) ? part[t] : 0;
    int ps = pv;
    for (int o = 32; o; o >>= 1) ps += __shfl_down(ps, o);
    __shared__ int sh[4];
    if ((t & 63) == 0) sh[t >> 6] = ps;
    __syncthreads();
    int blockoff = sh[0] + sh[1] + sh[2] + sh[3];

    int base = b * SCAN_CHUNK + t * 4;
    int v0 = 0, v1 = 0, v2 = 0, v3 = 0;
    if (base + 0 < m) v0 = in[base + 0];
    if (base + 1 < m) v1 = in[base + 1];
    if (base + 2 < m) v2 = in[base + 2];
    if (base + 3 < m) v3 = in[base + 3];
    int tot = v0 + v1 + v2 + v3;
    int lane = t & 63, wid = t >> 6;
    int incl = tot;
    for (int o = 1; o < 64; o <<= 1) { int u = __shfl_up(incl, o); if (lane >= o) incl += u; }
    int excl = incl - tot;
    __shared__ int wt[4];
    if (lane == 63) wt[wid] = incl;
    __syncthreads();
    int woff = 0;
    for (int w = 0; w < wid; ++w) woff += wt[w];
    int off = blockoff + woff + excl;
    if (base + 0 < m) out[base + 0] = off;
    if (base + 1 < m) out[base + 1] = off + v0;
    if (base + 2 < m) out[base + 2] = off + v0 + v1;
    if (base + 3 < m) out[base + 3] = off + v0 + v1 + v2;
}

// ---- pass 1a: per-block bucket histogram (LDS atomics only) ----
__global__ __launch_bounds__(256) void k_hist(const int* __restrict__ dst,
                                              int* __restrict__ ghist,
                                              int e, int echunk, int nbuck) {
    extern __shared__ int h[];   // nbuck ints
    int t = threadIdx.x, b = blockIdx.x;
    for (int i = t; i < nbuck; i += 256) h[i] = 0;
    __syncthreads();
    int s = b * echunk, epd = min(e, s + echunk);
    for (int i = s + t; i < epd; i += 256)
        atomicAdd(&h[dst[i] >> BSHIFT], 1);
    __syncthreads();
    for (int k = t; k < nbuck; k += 256)
        ghist[k * B1 + b] = h[k];
}

// ---- pass 1b: scatter packed (src<<7|dlow) into bucket-ordered ebuf ----
__global__ __launch_bounds__(256) void k_binscatter(
        const int* __restrict__ src, const int* __restrict__ dst,
        const int* __restrict__ ghist_s, int* __restrict__ ebuf,
        int e, int echunk, int nbuck) {
    extern __shared__ int cur[];   // nbuck ints
    int t = threadIdx.x, b = blockIdx.x;
    for (int k = t; k < nbuck; k += 256)
        cur[k] = ghist_s[k * B1 + b];
    __syncthreads();
    int s = b * echunk, epd = min(e, s + echunk);
    for (int i = s + t; i < epd; i += 256) {
        int d = dst[i];
        int pos = atomicAdd(&cur[d >> BSHIFT], 1);
        ebuf[pos] = (src[i] << BSHIFT) | (d & (BSIZE - 1));
    }
}

// ---- pass 2: per-bucket dst counting sort -> ebuf2 (bucket-local CSR) ----
__global__ __launch_bounds__(256) void k_csr(
        const int* __restrict__ ebuf, const int* __restrict__ ghist_s,
        int* __restrict__ ebuf2, int* __restrict__ rowptr, int* __restrict__ degi,
        float* __restrict__ dis, int n, int e, int nbuck) {
    int k = blockIdx.x, t = threadIdx.x;
    int estart = ghist_s[k * B1];
    int eend = (k + 1 < nbuck) ? ghist_s[(k + 1) * B1] : e;
    __shared__ int cnt[BSIZE];
    __shared__ int cur[BSIZE];
    __shared__ int wt[4];
    if (t < BSIZE) cnt[t] = 0;
    __syncthreads();
    for (int i = estart + t; i < eend; i += 256)
        atomicAdd(&cnt[ebuf[i] & (BSIZE - 1)], 1);
    __syncthreads();
    int v = (t < BSIZE) ? cnt[t] : 0;
    int lane = t & 63, wid = t >> 6;
    int incl = v;
    for (int o = 1; o < 64; o <<= 1) { int u = __shfl_up(incl, o); if (lane >= o) incl += u; }
    if (lane == 63) wt[wid] = incl;
    __syncthreads();
    int woff = (wid == 1) ? wt[0] : 0;
    int excl = woff + incl - v;
    if (t < BSIZE) {
        cur[t] = estart + excl;
        int node = k * BSIZE + t;
        if (node < n) {
            rowptr[node] = estart + excl;
            degi[node]   = v;
            dis[node]    = rsqrtf((float)(v + 1));
        }
    }
    __syncthreads();
    for (int i = estart + t; i < eend; i += 256) {
        int w = ebuf[i];
        int pos = atomicAdd(&cur[w & (BSIZE - 1)], 1);
        ebuf2[pos] = w;      // packed (src<<7 | dlow), dst-sorted
    }
}

// h1s = (x @ W1) * dis — outer-product GEMM, block tile 64x64, K=128.
#define SA 132
__global__ __launch_bounds__(256) void k_gemm1(
        const float* __restrict__ x, const float* __restrict__ W1,
        const float* __restrict__ dis, float* __restrict__ h1s, int n) {
    __shared__ float Xs[64 * SA];    // 33 KB
    __shared__ float Ws[128 * 64];   // 32 KB
    int t = threadIdx.x;
    int nbase = blockIdx.x * 64;
    for (int i = t; i < 2048; i += 256)
        ((float4*)Ws)[i] = ((const float4*)W1)[i];
    for (int i = t; i < 2048; i += 256) {
        int row = i >> 5, q = i & 31;
        int r = nbase + row; if (r >= n) r = n - 1;
        float4 v = ((const float4*)(x + (size_t)r * 128))[q];
        *(float4*)&Xs[row * SA + q * 4] = v;
    }
    __syncthreads();
    int wid = t >> 6, lane = t & 63;
    int lx = lane & 7, ly = lane >> 3;
    int wm = wid & 1, wn = wid >> 1;
    int row0 = wm * 32 + ly * 4;
    int col0 = wn * 32 + lx * 4;
    float4 acc0 = {0.f,0.f,0.f,0.f}, acc1 = acc0, acc2 = acc0, acc3 = acc0;
#pragma unroll 4
    for (int k4 = 0; k4 < 32; ++k4) {
        int k = k4 * 4;
        float4 a0 = *(const float4*)&Xs[(row0 + 0) * SA + k];
        float4 a1 = *(const float4*)&Xs[(row0 + 1) * SA + k];
        float4 a2 = *(const float4*)&Xs[(row0 + 2) * SA + k];
        float4 a3 = *(const float4*)&Xs[(row0 + 3) * SA + k];
        float4 b0 = *(const float4*)&Ws[(k + 0) * 64 + col0];
        float4 b1 = *(const float4*)&Ws[(k + 1) * 64 + col0];
        float4 b2 = *(const float4*)&Ws[(k + 2) * 64 + col0];
        float4 b3 = *(const float4*)&Ws[(k + 3) * 64 + col0];
        f4fma(acc0, a0.x, b0); f4fma(acc0, a0.y, b1); f4fma(acc0, a0.z, b2); f4fma(acc0, a0.w, b3);
        f4fma(acc1, a1.x, b0); f4fma(acc1, a1.y, b1); f4fma(acc1, a1.z, b2); f4fma(acc1, a1.w, b3);
        f4fma(acc2, a2.x, b0); f4fma(acc2, a2.y, b1); f4fma(acc2, a2.z, b2); f4fma(acc2, a2.w, b3);
        f4fma(acc3, a3.x, b0); f4fma(acc3, a3.y, b1); f4fma(acc3, a3.z, b2); f4fma(acc3, a3.w, b3);
    }
    int grow = nbase + row0;
#pragma unroll
    for (int r = 0; r < 4; ++r) {
        int rr = grow + r;
        if (rr < n) {
            float d = dis[rr];
            float4 o = (r == 0) ? acc0 : (r == 1) ? acc1 : (r == 2) ? acc2 : acc3;
            o.x *= d; o.y *= d; o.z *= d; o.w *= d;
            *(float4*)&h1s[(size_t)rr * 64 + col0] = o;
        }
    }
}

// Layer-1 aggregation + relu/b1 + gemm2, all in-wave.  Wave per dst node:
// gather phase = round-6 structure (eg = lane>>4 edge slot, fq = (lane&15)*4
// feature quad; one dwordx4 covers 4 edges x 256 B).  After xor-reduce,
// lanes 0-15 hold the h1r row -> relu -> park in per-wave LDS row ->
// every lane computes one h2 column via register-resident W2 column.
__global__ __launch_bounds__(256) void k_agg12(
        const float* __restrict__ h1s, const int* __restrict__ ents,
        const int* __restrict__ rowptr, const int* __restrict__ degi,
        const float* __restrict__ dis, const float* __restrict__ b1,
        const float* __restrict__ W2, float* __restrict__ h2s, int n) {
    __shared__ float h1row[4][68];
    int wid = threadIdx.x >> 6, lane = threadIdx.x & 63;
    int v = blockIdx.x * 4 + wid;
    int vc = min(v, n - 1);            // no early return (syncthreads below)
    int start = rowptr[vc], cnt = degi[vc];
    int eg = lane >> 4;
    int fq = (lane & 15) * 4;
    int c = lane & 31, hh = lane >> 5;
    // preload W2 column c, k-range [hh*32, hh*32+32) -> 32 VGPRs
    float w2r[32];
#pragma unroll
    for (int j = 0; j < 32; ++j)
        w2r[j] = W2[(hh * 32 + j) * 32 + c];
    float4 acc = {0.f, 0.f, 0.f, 0.f};
    if (cnt > 0 && cnt <= 64) {
        int pre = ents[start + min(lane, cnt - 1)];
        int ng = cnt >> 2;
#pragma unroll 4
        for (int g = 0; g < ng; ++g) {
            unsigned s = ((unsigned)__shfl(pre, g * 4 + eg)) >> BSHIFT;
            f4add(acc, *(const float4*)&h1s[(size_t)s * 64 + fq]);
        }
        int rem = cnt & 3, j0 = cnt & ~3;
        if (rem) {
            unsigned s = ((unsigned)__shfl(pre, j0 + (eg < rem ? eg : 0))) >> BSHIFT;
            float4 a = *(const float4*)&h1s[(size_t)s * 64 + fq];
            if (eg < rem) f4add(acc, a);
        }
    } else if (cnt > 64) {
        int j = 0;
        for (; j + 4 <= cnt; j += 4) {
            unsigned s = ((unsigned)ents[start + j + eg]) >> BSHIFT;
            f4add(acc, *(const float4*)&h1s[(size_t)s * 64 + fq]);
        }
        int rem = cnt - j;
        if (rem) {
            unsigned s = ((unsigned)ents[start + j + (eg < rem ? eg : 0)]) >> BSHIFT;
            float4 a = *(const float4*)&h1s[(size_t)s * 64 + fq];
            if (eg < rem) f4add(acc, a);
        }
    }
    if (eg == 0) f4add(acc, *(const float4*)&h1s[(size_t)vc * 64 + fq]);  // self
    f4red(acc, 16); f4red(acc, 32);
    float d = dis[vc];
    if (eg == 0) {
        float4 bq = *(const float4*)&b1[fq];
        float4 o;
        o.x = fmaxf(fmaf(d, acc.x, bq.x), 0.f);
        o.y = fmaxf(fmaf(d, acc.y, bq.y), 0.f);
        o.z = fmaxf(fmaf(d, acc.z, bq.z), 0.f);
        o.w = fmaxf(fmaf(d, acc.w, bq.w), 0.f);
        *(float4*)&h1row[wid][fq] = o;
    }
    __syncthreads();     // orders each wave's LDS row write before its reads
    // gemm2 in-wave: lane computes h2[c] partial over its k-half
    float p = 0.f;
#pragma unroll
    for (int j = 0; j < 32; j += 4) {
        float4 hv = *(const float4*)&h1row[wid][hh * 32 + j];
        p = fmaf(hv.x, w2r[j + 0], p);
        p = fmaf(hv.y, w2r[j + 1], p);
        p = fmaf(hv.z, w2r[j + 2], p);
        p = fmaf(hv.w, w2r[j + 3], p);
    }
    p += __shfl_xor(p, 32);
    if (hh == 0 && v < n) h2s[(size_t)v * 32 + c] = p * d;
}

// layer-2 aggregation + relu + FC head (round-6 proven structure).
// wave per dst; eg = lane>>3 (8 edge slots), fq = (lane&7)*4.
__global__ void k_agg2(const float* __restrict__ h2s, const int* __restrict__ ents,
                       const int* __restrict__ rowptr, const int* __restrict__ degi,
                       const float* __restrict__ dis, const float* __restrict__ b2,
                       const float* __restrict__ Wfc, const float* __restrict__ bfc,
                       float* __restrict__ out, int n) {
    int wid = threadIdx.x >> 6, lane = threadIdx.x & 63;
    int v = blockIdx.x * 4 + wid;
    if (v >= n) return;
    int start = rowptr[v], cnt = degi[v];
    int eg = lane >> 3;
    int fq = (lane & 7) * 4;
    float4 acc = {0.f, 0.f, 0.f, 0.f};
    if (cnt > 0 && cnt <= 64) {
        int pre = ents[start + min(lane, cnt - 1)];
        int ng = cnt >> 3;
#pragma unroll 4
        for (int g = 0; g < ng; ++g) {
            unsigned s = ((unsigned)__shfl(pre, g * 8 + eg)) >> BSHIFT;
            f4add(acc, *(const float4*)&h2s[(size_t)s * 32 + fq]);
        }
        int rem = cnt & 7, j0 = cnt & ~7;
        if (rem) {
            unsigned s = ((unsigned)__shfl(pre, j0 + (eg < rem ? eg : 0))) >> BSHIFT;
            float4 a = *(const float4*)&h2s[(size_t)s * 32 + fq];
            if (eg < rem) f4add(acc, a);
        }
    } else if (cnt > 64) {
        int j = 0;
        for (; j + 8 <= cnt; j += 8) {
            unsigned s = ((unsigned)ents[start + j + eg]) >> BSHIFT;
            f4add(acc, *(const float4*)&h2s[(size_t)s * 32 + fq]);
        }
        int rem = cnt - j;
        if (rem) {
            unsigned s = ((unsigned)ents[start + j + (eg < rem ? eg : 0)]) >> BSHIFT;
            float4 a = *(const float4*)&h2s[(size_t)s * 32 + fq];
            if (eg < rem) f4add(acc, a);
        }
    }
    if (eg == 0) f4add(acc, *(const float4*)&h2s[(size_t)v * 32 + fq]);  // self
    f4red(acc, 8); f4red(acc, 16); f4red(acc, 32);
    float p = 0.f;
    if (eg == 0) {
        float d = dis[v];
        float4 bq = *(const float4*)&b2[fq];
        float4 wq = *(const float4*)&Wfc[fq];
        p  = fmaxf(fmaf(d, acc.x, bq.x), 0.f) * wq.x;
        p += fmaxf(fmaf(d, acc.y, bq.y), 0.f) * wq.y;
        p += fmaxf(fmaf(d, acc.z, bq.z), 0.f) * wq.z;
        p += fmaxf(fmaf(d, acc.w, bq.w), 0.f) * wq.w;
    }
    p += __shfl_xor(p, 1); p += __shfl_xor(p, 2); p += __shfl_xor(p, 4);
    if (lane == 0) out[v] = p + bfc[0];
}

extern "C" void kernel_launch(void* const* d_in, const int* in_sizes, int n_in,
                              void* d_out, int out_size, void* d_ws, size_t ws_size,
                              hipStream_t stream) {
    const float* x   = (const float*)d_in[0];
    const int*   ei  = (const int*)d_in[1];
    const float* W1  = (const float*)d_in[2];
    const float* b1  = (const float*)d_in[3];
    const float* W2  = (const float*)d_in[4];
    const float* b2  = (const float*)d_in[5];
    const float* Wfc = (const float*)d_in[6];
    const float* bfc = (const float*)d_in[7];
    float* out = (float*)d_out;

    const int n = in_sizes[0] / 128;       // 100000
    const int e = in_sizes[1] / 2;         // 3200000
    const int* src = ei;
    const int* dst = ei + e;

    const int nbuck = (n + BSIZE - 1) / BSIZE;           // 782
    const int m = nbuck * B1;                            // 200192
    const int echunk = (e + B1 - 1) / B1;                // 12500

    char* p = (char*)d_ws;
    size_t off = 0;
    auto carve = [&](size_t bytes) { void* r = p + off; off = (off + bytes + 255) & ~(size_t)255; return r; };
    int*   ghist   = (int*)  carve((size_t)m * 4);
    int*   ghist_s = (int*)  carve((size_t)m * 4);
    int*   part    = (int*)  carve(256 * 4);
    float* dis     = (float*)carve((size_t)n * 4);
    int*   rowptr  = (int*)  carve((size_t)n * 4);
    int*   degi    = (int*)  carve((size_t)n * 4);
    int*   ebuf2   = (int*)  carve((size_t)e * 4);
    float* h2s     = (float*)carve((size_t)n * 32 * 4);
    void*  ebuf_or_h1s = carve((size_t)n * 64 * 4);      // ebuf(E*4) aliases h1s
    int*   ebuf = (int*)ebuf_or_h1s;
    float* h1s  = (float*)ebuf_or_h1s;
    (void)ws_size;

    const int nblk_scan = (m + SCAN_CHUNK - 1) / SCAN_CHUNK;   // 196 (<=256)
    const size_t lds_buck = (size_t)nbuck * 4;

    k_hist<<<B1, 256, lds_buck, stream>>>(dst, ghist, e, echunk, nbuck);
    k_gscan1<<<nblk_scan, 256, 0, stream>>>(ghist, part, m);
    k_gscan2<<<nblk_scan, 256, 0, stream>>>(ghist, part, ghist_s, m, nblk_scan);
    k_binscatter<<<B1, 256, lds_buck, stream>>>(src, dst, ghist_s, ebuf, e, echunk, nbuck);
    k_csr<<<nbuck, 256, 0, stream>>>(ebuf, ghist_s, ebuf2, rowptr, degi, dis, n, e, nbuck);
    k_gemm1<<<(n + 63) / 64, 256, 0, stream>>>(x, W1, dis, h1s, n);
    k_agg12<<<(n + 3) / 4, 256, 0, stream>>>(h1s, ebuf2, rowptr, degi, dis, b1, W2, h2s, n);
    k_agg2<<<(n + 3) / 4, 256, 0, stream>>>(h2s, ebuf2, rowptr, degi, dis, b2, Wfc, bfc, out, n);
}

// Round 11
// 348.292 us; speedup vs baseline: 6.7570x; 1.1006x over previous
//
#include <hip/hip_runtime.h>
#include <hip/hip_bf16.h>
#include <hip/hip_fp16.h>

// GCN: h = relu(GCN(x,W1,b1)); h = relu(GCN(h,W2,b2)); out = h @ Wfc + bfc
// GCN(x,W,b)[d] = dis[d] * ( sum_{(s,d) in E} hs[s] + hs[d] ) + b
//   where hs[v] = (x[v]@W) * dis[v],  dis[v] = rsqrt(1 + indeg(v))
//
// Round-11: identical structure to round-10 (binned counting sort -> packed
// dst-sorted CSR; layer-1 multi-edge gather + in-wave relu/b1/gemm2; layer-2
// multi-edge gather + relu/b2/FC) but the two intermediate tensors h1s/h2s
// are stored FP16 (compute stays fp32).  Both aggregations are at the
// L2-miss-byte wall (~3.4 TB/s on 362 MB) -- halving stored bytes halves it.

#define SCAN_CHUNK 1024
#define BSHIFT 7
#define BSIZE 128            // dsts per bucket
#define B1 256               // blocks in hist/binscatter passes

__device__ inline void f4fma(float4& a, float s, const float4& b) {
    a.x = fmaf(s, b.x, a.x); a.y = fmaf(s, b.y, a.y);
    a.z = fmaf(s, b.z, a.z); a.w = fmaf(s, b.w, a.w);
}
__device__ inline void f4add(float4& a, const float4& b) {
    a.x += b.x; a.y += b.y; a.z += b.z; a.w += b.w;
}
__device__ inline void f4red(float4& a, int off) {
    a.x += __shfl_xor(a.x, off); a.y += __shfl_xor(a.y, off);
    a.z += __shfl_xor(a.z, off); a.w += __shfl_xor(a.w, off);
}
// 4 halves <-> float4 (single 8-B load/store)
__device__ inline float4 h4load(const __half* p) {
    uint2 r = *(const uint2*)p;
    __half2 a = *(__half2*)&r.x;
    __half2 b = *(__half2*)&r.y;
    float2 fa = __half22float2(a), fb = __half22float2(b);
    return make_float4(fa.x, fa.y, fb.x, fb.y);
}
__device__ inline void h4store(__half* p, float4 v) {
    __half2 a = __floats2half2_rn(v.x, v.y);
    __half2 b = __floats2half2_rn(v.z, v.w);
    uint2 r; r.x = *(uint*)&a; r.y = *(uint*)&b;
    *(uint2*)p = r;
}

// ---- generic exclusive scan (m ints, nblk = ceil(m/1024) <= 256) ----
__global__ void k_gscan1(const int* __restrict__ in, int* __restrict__ part, int m) {
    int t = threadIdx.x;
    int base = blockIdx.x * SCAN_CHUNK + t * 4;
    int s = 0;
    for (int u = 0; u < 4; ++u) { int i = base + u; if (i < m) s += in[i]; }
    for (int o = 32; o; o >>= 1) s += __shfl_down(s, o);
    __shared__ int ws[4];
    if ((t & 63) == 0) ws[t >> 6] = s;
    __syncthreads();
    if (t == 0) part[blockIdx.x] = ws[0] + ws[1] + ws[2] + ws[3];
}

__global__ void k_gscan2(const int* __restrict__ in, const int* __restrict__ part,
                         int* __restrict__ out, int m, int nblk) {
    int t = threadIdx.x;
    int b = blockIdx.x;
    int pv = (t < b && t < nblk) ? part[t] : 0;
    int ps = pv;
    for (int o = 32; o; o >>= 1) ps += __shfl_down(ps, o);
    __shared__ int sh[4];
    if ((t & 63) == 0) sh[t >> 6] = ps;
    __syncthreads();
    int blockoff = sh[0] + sh[1] + sh[2] + sh[3];

    int base = b * SCAN_CHUNK + t * 4;
    int v0 = 0, v1 = 0, v2 = 0, v3 = 0;
    if (base + 0 < m) v0 = in[base + 0];
    if (base + 1 < m) v1 = in[base + 1];
    if (base + 2 < m) v2 = in[base + 2];
    if (base + 3 < m) v3 = in[base + 3];
    int tot = v0 + v1 + v2 + v3;
    int lane = t & 63, wid = t >> 6;
    int incl = tot;
    for (int o = 1; o < 64; o <<= 1) { int u = __shfl_up(incl, o); if (lane >= o) incl += u; }
    int excl = incl - tot;
    __shared__ int wt[4];
    if (lane == 63) wt[wid] = incl;
    __syncthreads();
    int woff = 0;
    for (int w = 0; w < wid; ++w) woff += wt[w];
    int off = blockoff + woff + excl;
    if (base + 0 < m) out[base + 0] = off;
    if (base + 1 < m) out[base + 1] = off + v0;
    if (base + 2 < m) out[base + 2] = off + v0 + v1;
    if (base + 3 < m) out[base + 3] = off + v0 + v1 + v2;
}

// ---- pass 1a: per-block bucket histogram (LDS atomics only) ----
__global__ __launch_bounds__(256) void k_hist(const int* __restrict__ dst,
                                              int* __restrict__ ghist,
                                              int e, int echunk, int nbuck) {
    extern __shared__ int h[];   // nbuck ints
    int t = threadIdx.x, b = blockIdx.x;
    for (int i = t; i < nbuck; i += 256) h[i] = 0;
    __syncthreads();
    int s = b * echunk, epd = min(e, s + echunk);
    for (int i = s + t; i < epd; i += 256)
        atomicAdd(&h[dst[i] >> BSHIFT], 1);
    __syncthreads();
    for (int k = t; k < nbuck; k += 256)
        ghist[k * B1 + b] = h[k];
}

// ---- pass 1b: scatter packed (src<<7|dlow) into bucket-ordered ebuf ----
__global__ __launch_bounds__(256) void k_binscatter(
        const int* __restrict__ src, const int* __restrict__ dst,
        const int* __restrict__ ghist_s, int* __restrict__ ebuf,
        int e, int echunk, int nbuck) {
    extern __shared__ int cur[];   // nbuck ints
    int t = threadIdx.x, b = blockIdx.x;
    for (int k = t; k < nbuck; k += 256)
        cur[k] = ghist_s[k * B1 + b];
    __syncthreads();
    int s = b * echunk, epd = min(e, s + echunk);
    for (int i = s + t; i < epd; i += 256) {
        int d = dst[i];
        int pos = atomicAdd(&cur[d >> BSHIFT], 1);
        ebuf[pos] = (src[i] << BSHIFT) | (d & (BSIZE - 1));
    }
}

// ---- pass 2: per-bucket dst counting sort -> ebuf2 (bucket-local CSR) ----
__global__ __launch_bounds__(256) void k_csr(
        const int* __restrict__ ebuf, const int* __restrict__ ghist_s,
        int* __restrict__ ebuf2, int* __restrict__ rowptr, int* __restrict__ degi,
        float* __restrict__ dis, int n, int e, int nbuck) {
    int k = blockIdx.x, t = threadIdx.x;
    int estart = ghist_s[k * B1];
    int eend = (k + 1 < nbuck) ? ghist_s[(k + 1) * B1] : e;
    __shared__ int cnt[BSIZE];
    __shared__ int cur[BSIZE];
    __shared__ int wt[4];
    if (t < BSIZE) cnt[t] = 0;
    __syncthreads();
    for (int i = estart + t; i < eend; i += 256)
        atomicAdd(&cnt[ebuf[i] & (BSIZE - 1)], 1);
    __syncthreads();
    int v = (t < BSIZE) ? cnt[t] : 0;
    int lane = t & 63, wid = t >> 6;
    int incl = v;
    for (int o = 1; o < 64; o <<= 1) { int u = __shfl_up(incl, o); if (lane >= o) incl += u; }
    if (lane == 63) wt[wid] = incl;
    __syncthreads();
    int woff = (wid == 1) ? wt[0] : 0;
    int excl = woff + incl - v;
    if (t < BSIZE) {
        cur[t] = estart + excl;
        int node = k * BSIZE + t;
        if (node < n) {
            rowptr[node] = estart + excl;
            degi[node]   = v;
            dis[node]    = rsqrtf((float)(v + 1));
        }
    }
    __syncthreads();
    for (int i = estart + t; i < eend; i += 256) {
        int w = ebuf[i];
        int pos = atomicAdd(&cur[w & (BSIZE - 1)], 1);
        ebuf2[pos] = w;      // packed (src<<7 | dlow), dst-sorted
    }
}

// h1s = fp16( (x @ W1) * dis ) — outer-product GEMM, block tile 64x64, K=128.
#define SA 132
__global__ __launch_bounds__(256) void k_gemm1(
        const float* __restrict__ x, const float* __restrict__ W1,
        const float* __restrict__ dis, __half* __restrict__ h1s, int n) {
    __shared__ float Xs[64 * SA];    // 33 KB
    __shared__ float Ws[128 * 64];   // 32 KB
    int t = threadIdx.x;
    int nbase = blockIdx.x * 64;
    for (int i = t; i < 2048; i += 256)
        ((float4*)Ws)[i] = ((const float4*)W1)[i];
    for (int i = t; i < 2048; i += 256) {
        int row = i >> 5, q = i & 31;
        int r = nbase + row; if (r >= n) r = n - 1;
        float4 v = ((const float4*)(x + (size_t)r * 128))[q];
        *(float4*)&Xs[row * SA + q * 4] = v;
    }
    __syncthreads();
    int wid = t >> 6, lane = t & 63;
    int lx = lane & 7, ly = lane >> 3;
    int wm = wid & 1, wn = wid >> 1;
    int row0 = wm * 32 + ly * 4;
    int col0 = wn * 32 + lx * 4;
    float4 acc0 = {0.f,0.f,0.f,0.f}, acc1 = acc0, acc2 = acc0, acc3 = acc0;
#pragma unroll 4
    for (int k4 = 0; k4 < 32; ++k4) {
        int k = k4 * 4;
        float4 a0 = *(const float4*)&Xs[(row0 + 0) * SA + k];
        float4 a1 = *(const float4*)&Xs[(row0 + 1) * SA + k];
        float4 a2 = *(const float4*)&Xs[(row0 + 2) * SA + k];
        float4 a3 = *(const float4*)&Xs[(row0 + 3) * SA + k];
        float4 b0 = *(const float4*)&Ws[(k + 0) * 64 + col0];
        float4 b1 = *(const float4*)&Ws[(k + 1) * 64 + col0];
        float4 b2 = *(const float4*)&Ws[(k + 2) * 64 + col0];
        float4 b3 = *(const float4*)&Ws[(k + 3) * 64 + col0];
        f4fma(acc0, a0.x, b0); f4fma(acc0, a0.y, b1); f4fma(acc0, a0.z, b2); f4fma(acc0, a0.w, b3);
        f4fma(acc1, a1.x, b0); f4fma(acc1, a1.y, b1); f4fma(acc1, a1.z, b2); f4fma(acc1, a1.w, b3);
        f4fma(acc2, a2.x, b0); f4fma(acc2, a2.y, b1); f4fma(acc2, a2.z, b2); f4fma(acc2, a2.w, b3);
        f4fma(acc3, a3.x, b0); f4fma(acc3, a3.y, b1); f4fma(acc3, a3.z, b2); f4fma(acc3, a3.w, b3);
    }
    int grow = nbase + row0;
#pragma unroll
    for (int r = 0; r < 4; ++r) {
        int rr = grow + r;
        if (rr < n) {
            float d = dis[rr];
            float4 o = (r == 0) ? acc0 : (r == 1) ? acc1 : (r == 2) ? acc2 : acc3;
            o.x *= d; o.y *= d; o.z *= d; o.w *= d;
            h4store(&h1s[(size_t)rr * 64 + col0], o);
        }
    }
}

// Layer-1 aggregation + relu/b1 + gemm2, all in-wave.  Wave per dst node:
// eg = lane>>4 edge slot (4), fq = (lane&15)*4 feature quad; one dwordx2
// per lane covers 4 edges x 128 B (fp16 rows).  After xor-reduce, lanes
// 0-15 hold the h1r row -> relu -> LDS row -> in-wave gemm2 -> h2s (fp16).
__global__ __launch_bounds__(256) void k_agg12(
        const __half* __restrict__ h1s, const int* __restrict__ ents,
        const int* __restrict__ rowptr, const int* __restrict__ degi,
        const float* __restrict__ dis, const float* __restrict__ b1,
        const float* __restrict__ W2, __half* __restrict__ h2s, int n) {
    __shared__ float h1row[4][68];
    int wid = threadIdx.x >> 6, lane = threadIdx.x & 63;
    int v = blockIdx.x * 4 + wid;
    int vc = min(v, n - 1);            // no early return (syncthreads below)
    int start = rowptr[vc], cnt = degi[vc];
    int eg = lane >> 4;
    int fq = (lane & 15) * 4;
    int c = lane & 31, hh = lane >> 5;
    // preload W2 column c, k-range [hh*32, hh*32+32) -> 32 VGPRs
    float w2r[32];
#pragma unroll
    for (int j = 0; j < 32; ++j)
        w2r[j] = W2[(hh * 32 + j) * 32 + c];
    float4 acc = {0.f, 0.f, 0.f, 0.f};
    if (cnt > 0 && cnt <= 64) {
        int pre = ents[start + min(lane, cnt - 1)];
        int ng = cnt >> 2;
#pragma unroll 4
        for (int g = 0; g < ng; ++g) {
            unsigned s = ((unsigned)__shfl(pre, g * 4 + eg)) >> BSHIFT;
            f4add(acc, h4load(&h1s[(size_t)s * 64 + fq]));
        }
        int rem = cnt & 3, j0 = cnt & ~3;
        if (rem) {
            unsigned s = ((unsigned)__shfl(pre, j0 + (eg < rem ? eg : 0))) >> BSHIFT;
            float4 a = h4load(&h1s[(size_t)s * 64 + fq]);
            if (eg < rem) f4add(acc, a);
        }
    } else if (cnt > 64) {
        int j = 0;
        for (; j + 4 <= cnt; j += 4) {
            unsigned s = ((unsigned)ents[start + j + eg]) >> BSHIFT;
            f4add(acc, h4load(&h1s[(size_t)s * 64 + fq]));
        }
        int rem = cnt - j;
        if (rem) {
            unsigned s = ((unsigned)ents[start + j + (eg < rem ? eg : 0)]) >> BSHIFT;
            float4 a = h4load(&h1s[(size_t)s * 64 + fq]);
            if (eg < rem) f4add(acc, a);
        }
    }
    if (eg == 0) f4add(acc, h4load(&h1s[(size_t)vc * 64 + fq]));  // self
    f4red(acc, 16); f4red(acc, 32);
    float d = dis[vc];
    if (eg == 0) {
        float4 bq = *(const float4*)&b1[fq];
        float4 o;
        o.x = fmaxf(fmaf(d, acc.x, bq.x), 0.f);
        o.y = fmaxf(fmaf(d, acc.y, bq.y), 0.f);
        o.z = fmaxf(fmaf(d, acc.z, bq.z), 0.f);
        o.w = fmaxf(fmaf(d, acc.w, bq.w), 0.f);
        *(float4*)&h1row[wid][fq] = o;
    }
    __syncthreads();     // orders each wave's LDS row write before its reads
    // gemm2 in-wave: lane computes h2[c] partial over its k-half
    float p = 0.f;
#pragma unroll
    for (int j = 0; j < 32; j += 4) {
        float4 hv = *(const float4*)&h1row[wid][hh * 32 + j];
        p = fmaf(hv.x, w2r[j + 0], p);
        p = fmaf(hv.y, w2r[j + 1], p);
        p = fmaf(hv.z, w2r[j + 2], p);
        p = fmaf(hv.w, w2r[j + 3], p);
    }
    p += __shfl_xor(p, 32);
    if (hh == 0 && v < n) h2s[(size_t)v * 32 + c] = __float2half(p * d);
}

// layer-2 aggregation + relu + FC head.  wave per dst; eg = lane>>3 (8 edge
// slots), fq = (lane&7)*4; one dwordx2 per lane covers 8 edges x 64 B rows.
__global__ void k_agg2(const __half* __restrict__ h2s, const int* __restrict__ ents,
                       const int* __restrict__ rowptr, const int* __restrict__ degi,
                       const float* __restrict__ dis, const float* __restrict__ b2,
                       const float* __restrict__ Wfc, const float* __restrict__ bfc,
                       float* __restrict__ out, int n) {
    int wid = threadIdx.x >> 6, lane = threadIdx.x & 63;
    int v = blockIdx.x * 4 + wid;
    if (v >= n) return;
    int start = rowptr[v], cnt = degi[v];
    int eg = lane >> 3;
    int fq = (lane & 7) * 4;
    float4 acc = {0.f, 0.f, 0.f, 0.f};
    if (cnt > 0 && cnt <= 64) {
        int pre = ents[start + min(lane, cnt - 1)];
        int ng = cnt >> 3;
#pragma unroll 4
        for (int g = 0; g < ng; ++g) {
            unsigned s = ((unsigned)__shfl(pre, g * 8 + eg)) >> BSHIFT;
            f4add(acc, h4load(&h2s[(size_t)s * 32 + fq]));
        }
        int rem = cnt & 7, j0 = cnt & ~7;
        if (rem) {
            unsigned s = ((unsigned)__shfl(pre, j0 + (eg < rem ? eg : 0))) >> BSHIFT;
            float4 a = h4load(&h2s[(size_t)s * 32 + fq]);
            if (eg < rem) f4add(acc, a);
        }
    } else if (cnt > 64) {
        int j = 0;
        for (; j + 8 <= cnt; j += 8) {
            unsigned s = ((unsigned)ents[start + j + eg]) >> BSHIFT;
            f4add(acc, h4load(&h2s[(size_t)s * 32 + fq]));
        }
        int rem = cnt - j;
        if (rem) {
            unsigned s = ((unsigned)ents[start + j + (eg < rem ? eg : 0)]) >> BSHIFT;
            float4 a = h4load(&h2s[(size_t)s * 32 + fq]);
            if (eg < rem) f4add(acc, a);
        }
    }
    if (eg == 0) f4add(acc, h4load(&h2s[(size_t)v * 32 + fq]));  // self
    f4red(acc, 8); f4red(acc, 16); f4red(acc, 32);
    float p = 0.f;
    if (eg == 0) {
        float d = dis[v];
        float4 bq = *(const float4*)&b2[fq];
        float4 wq = *(const float4*)&Wfc[fq];
        p  = fmaxf(fmaf(d, acc.x, bq.x), 0.f) * wq.x;
        p += fmaxf(fmaf(d, acc.y, bq.y), 0.f) * wq.y;
        p += fmaxf(fmaf(d, acc.z, bq.z), 0.f) * wq.z;
        p += fmaxf(fmaf(d, acc.w, bq.w), 0.f) * wq.w;
    }
    p += __shfl_xor(p, 1); p += __shfl_xor(p, 2); p += __shfl_xor(p, 4);
    if (lane == 0) out[v] = p + bfc[0];
}

extern "C" void kernel_launch(void* const* d_in, const int* in_sizes, int n_in,
                              void* d_out, int out_size, void* d_ws, size_t ws_size,
                              hipStream_t stream) {
    const float* x   = (const float*)d_in[0];
    const int*   ei  = (const int*)d_in[1];
    const float* W1  = (const float*)d_in[2];
    const float* b1  = (const float*)d_in[3];
    const float* W2  = (const float*)d_in[4];
    const float* b2  = (const float*)d_in[5];
    const float* Wfc = (const float*)d_in[6];
    const float* bfc = (const float*)d_in[7];
    float* out = (float*)d_out;

    const int n = in_sizes[0] / 128;       // 100000
    const int e = in_sizes[1] / 2;         // 3200000
    const int* src = ei;
    const int* dst = ei + e;

    const int nbuck = (n + BSIZE - 1) / BSIZE;           // 782
    const int m = nbuck * B1;                            // 200192
    const int echunk = (e + B1 - 1) / B1;                // 12500

    char* p = (char*)d_ws;
    size_t off = 0;
    auto carve = [&](size_t bytes) { void* r = p + off; off = (off + bytes + 255) & ~(size_t)255; return r; };
    int*   ghist   = (int*)  carve((size_t)m * 4);
    int*   ghist_s = (int*)  carve((size_t)m * 4);
    int*   part    = (int*)  carve(256 * 4);
    float* dis     = (float*)carve((size_t)n * 4);
    int*   rowptr  = (int*)  carve((size_t)n * 4);
    int*   degi    = (int*)  carve((size_t)n * 4);
    int*   ebuf2   = (int*)  carve((size_t)e * 4);
    __half* h2s    = (__half*)carve((size_t)n * 32 * 2);
    void*  ebuf_or_h1s = carve((size_t)e * 4);           // ebuf(E*4) aliases h1s(N*64*2)
    int*    ebuf = (int*)ebuf_or_h1s;
    __half* h1s  = (__half*)ebuf_or_h1s;
    (void)ws_size;

    const int nblk_scan = (m + SCAN_CHUNK - 1) / SCAN_CHUNK;   // 196 (<=256)
    const size_t lds_buck = (size_t)nbuck * 4;

    k_hist<<<B1, 256, lds_buck, stream>>>(dst, ghist, e, echunk, nbuck);
    k_gscan1<<<nblk_scan, 256, 0, stream>>>(ghist, part, m);
    k_gscan2<<<nblk_scan, 256, 0, stream>>>(ghist, part, ghist_s, m, nblk_scan);
    k_binscatter<<<B1, 256, lds_buck, stream>>>(src, dst, ghist_s, ebuf, e, echunk, nbuck);
    k_csr<<<nbuck, 256, 0, stream>>>(ebuf, ghist_s, ebuf2, rowptr, degi, dis, n, e, nbuck);
    k_gemm1<<<(n + 63) / 64, 256, 0, stream>>>(x, W1, dis, h1s, n);
    k_agg12<<<(n + 3) / 4, 256, 0, stream>>>(h1s, ebuf2, rowptr, degi, dis, b1, W2, h2s, n);
    k_agg2<<<(n + 3) / 4, 256, 0, stream>>>(h2s, ebuf2, rowptr, degi, dis, b2, Wfc, bfc, out, n);
}

// Round 12
// 311.974 us; speedup vs baseline: 7.5437x; 1.1164x over previous
//
#include <hip/hip_runtime.h>
#include <hip/hip_bf16.h>
#include <hip/hip_fp16.h>

// GCN: h = relu(GCN(x,W1,b1)); h = relu(GCN(h,W2,b2)); out = h @ Wfc + bfc
// GCN(x,W,b)[d] = dis[d] * ( sum_{(s,d) in E} hs[s] + hs[d] ) + b
//   where hs[v] = (x[v]@W) * dis[v],  dis[v] = rsqrt(1 + indeg(v))
//
// Round-12: round-11 structure (binned counting sort -> packed dst-sorted
// CSR; fused gather kernels; fp16 h1s/h2s) with wider gathers now that the
// fetch wall is gone: agg12 = 8 edges per dwordx4 (fp16 row = 8 lanes x 16B),
// agg2 = 16 edges per dwordx4.  hist/binscatter use int4 edge reads.

#define SCAN_CHUNK 1024
#define BSHIFT 7
#define BSIZE 128            // dsts per bucket
#define B1 256               // blocks in hist/binscatter passes

__device__ inline void f4fma(float4& a, float s, const float4& b) {
    a.x = fmaf(s, b.x, a.x); a.y = fmaf(s, b.y, a.y);
    a.z = fmaf(s, b.z, a.z); a.w = fmaf(s, b.w, a.w);
}
__device__ inline void f4add(float4& a, const float4& b) {
    a.x += b.x; a.y += b.y; a.z += b.z; a.w += b.w;
}
__device__ inline void f4red(float4& a, int off) {
    a.x += __shfl_xor(a.x, off); a.y += __shfl_xor(a.y, off);
    a.z += __shfl_xor(a.z, off); a.w += __shfl_xor(a.w, off);
}
// 8 halves (16 B) -> two float4 (single dwordx4 load)
__device__ inline void h8load(const __half* p, float4& a, float4& b) {
    uint4 r = *(const uint4*)p;
    __half2* h = (__half2*)&r;
    float2 f0 = __half22float2(h[0]);
    float2 f1 = __half22float2(h[1]);
    float2 f2 = __half22float2(h[2]);
    float2 f3 = __half22float2(h[3]);
    a = make_float4(f0.x, f0.y, f1.x, f1.y);
    b = make_float4(f2.x, f2.y, f3.x, f3.y);
}
__device__ inline void h4store(__half* p, float4 v) {
    __half2 a = __floats2half2_rn(v.x, v.y);
    __half2 b = __floats2half2_rn(v.z, v.w);
    uint2 r; r.x = *(uint*)&a; r.y = *(uint*)&b;
    *(uint2*)p = r;
}

// ---- generic exclusive scan (m ints, nblk = ceil(m/1024) <= 256) ----
__global__ void k_gscan1(const int* __restrict__ in, int* __restrict__ part, int m) {
    int t = threadIdx.x;
    int base = blockIdx.x * SCAN_CHUNK + t * 4;
    int s = 0;
    for (int u = 0; u < 4; ++u) { int i = base + u; if (i < m) s += in[i]; }
    for (int o = 32; o; o >>= 1) s += __shfl_down(s, o);
    __shared__ int ws[4];
    if ((t & 63) == 0) ws[t >> 6] = s;
    __syncthreads();
    if (t == 0) part[blockIdx.x] = ws[0] + ws[1] + ws[2] + ws[3];
}

__global__ void k_gscan2(const int* __restrict__ in, const int* __restrict__ part,
                         int* __restrict__ out, int m, int nblk) {
    int t = threadIdx.x;
    int b = blockIdx.x;
    int pv = (t < b && t < nblk) ? part[t] : 0;
    int ps = pv;
    for (int o = 32; o; o >>= 1) ps += __shfl_down(ps, o);
    __shared__ int sh[4];
    if ((t & 63) == 0) sh[t >> 6] = ps;
    __syncthreads();
    int blockoff = sh[0] + sh[1] + sh[2] + sh[3];

    int base = b * SCAN_CHUNK + t * 4;
    int v0 = 0, v1 = 0, v2 = 0, v3 = 0;
    if (base + 0 < m) v0 = in[base + 0];
    if (base + 1 < m) v1 = in[base + 1];
    if (base + 2 < m) v2 = in[base + 2];
    if (base + 3 < m) v3 = in[base + 3];
    int tot = v0 + v1 + v2 + v3;
    int lane = t & 63, wid = t >> 6;
    int incl = tot;
    for (int o = 1; o < 64; o <<= 1) { int u = __shfl_up(incl, o); if (lane >= o) incl += u; }
    int excl = incl - tot;
    __shared__ int wt[4];
    if (lane == 63) wt[wid] = incl;
    __syncthreads();
    int woff = 0;
    for (int w = 0; w < wid; ++w) woff += wt[w];
    int off = blockoff + woff + excl;
    if (base + 0 < m) out[base + 0] = off;
    if (base + 1 < m) out[base + 1] = off + v0;
    if (base + 2 < m) out[base + 2] = off + v0 + v1;
    if (base + 3 < m) out[base + 3] = off + v0 + v1 + v2;
}

// ---- pass 1a: per-block bucket histogram (LDS atomics, int4 reads) ----
__global__ __launch_bounds__(256) void k_hist(const int* __restrict__ dst,
                                              int* __restrict__ ghist,
                                              int e, int echunk, int nbuck) {
    extern __shared__ int h[];   // nbuck ints
    int t = threadIdx.x, b = blockIdx.x;
    for (int i = t; i < nbuck; i += 256) h[i] = 0;
    __syncthreads();
    int s = b * echunk, epd = min(e, s + echunk);
    for (int i = s + t * 4; i < epd; i += 1024) {
        if (i + 3 < epd) {
            int4 d4 = *(const int4*)&dst[i];
            atomicAdd(&h[d4.x >> BSHIFT], 1);
            atomicAdd(&h[d4.y >> BSHIFT], 1);
            atomicAdd(&h[d4.z >> BSHIFT], 1);
            atomicAdd(&h[d4.w >> BSHIFT], 1);
        } else {
            for (int u = i; u < epd; ++u) atomicAdd(&h[dst[u] >> BSHIFT], 1);
        }
    }
    __syncthreads();
    for (int k = t; k < nbuck; k += 256)
        ghist[k * B1 + b] = h[k];
}

// ---- pass 1b: scatter packed (src<<7|dlow) into bucket-ordered ebuf ----
__global__ __launch_bounds__(256) void k_binscatter(
        const int* __restrict__ src, const int* __restrict__ dst,
        const int* __restrict__ ghist_s, int* __restrict__ ebuf,
        int e, int echunk, int nbuck) {
    extern __shared__ int cur[];   // nbuck ints
    int t = threadIdx.x, b = blockIdx.x;
    for (int k = t; k < nbuck; k += 256)
        cur[k] = ghist_s[k * B1 + b];
    __syncthreads();
    int s = b * echunk, epd = min(e, s + echunk);
    for (int i = s + t * 4; i < epd; i += 1024) {
        if (i + 3 < epd) {
            int4 d4 = *(const int4*)&dst[i];
            int4 s4 = *(const int4*)&src[i];
            int p0 = atomicAdd(&cur[d4.x >> BSHIFT], 1);
            int p1 = atomicAdd(&cur[d4.y >> BSHIFT], 1);
            int p2 = atomicAdd(&cur[d4.z >> BSHIFT], 1);
            int p3 = atomicAdd(&cur[d4.w >> BSHIFT], 1);
            ebuf[p0] = (s4.x << BSHIFT) | (d4.x & (BSIZE - 1));
            ebuf[p1] = (s4.y << BSHIFT) | (d4.y & (BSIZE - 1));
            ebuf[p2] = (s4.z << BSHIFT) | (d4.z & (BSIZE - 1));
            ebuf[p3] = (s4.w << BSHIFT) | (d4.w & (BSIZE - 1));
        } else {
            for (int u = i; u < epd; ++u) {
                int d = dst[u];
                int pos = atomicAdd(&cur[d >> BSHIFT], 1);
                ebuf[pos] = (src[u] << BSHIFT) | (d & (BSIZE - 1));
            }
        }
    }
}

// ---- pass 2: per-bucket dst counting sort -> ebuf2 (bucket-local CSR) ----
__global__ __launch_bounds__(256) void k_csr(
        const int* __restrict__ ebuf, const int* __restrict__ ghist_s,
        int* __restrict__ ebuf2, int* __restrict__ rowptr, int* __restrict__ degi,
        float* __restrict__ dis, int n, int e, int nbuck) {
    int k = blockIdx.x, t = threadIdx.x;
    int estart = ghist_s[k * B1];
    int eend = (k + 1 < nbuck) ? ghist_s[(k + 1) * B1] : e;
    __shared__ int cnt[BSIZE];
    __shared__ int cur[BSIZE];
    __shared__ int wt[4];
    if (t < BSIZE) cnt[t] = 0;
    __syncthreads();
    for (int i = estart + t; i < eend; i += 256)
        atomicAdd(&cnt[ebuf[i] & (BSIZE - 1)], 1);
    __syncthreads();
    int v = (t < BSIZE) ? cnt[t] : 0;
    int lane = t & 63, wid = t >> 6;
    int incl = v;
    for (int o = 1; o < 64; o <<= 1) { int u = __shfl_up(incl, o); if (lane >= o) incl += u; }
    if (lane == 63) wt[wid] = incl;
    __syncthreads();
    int woff = (wid == 1) ? wt[0] : 0;
    int excl = woff + incl - v;
    if (t < BSIZE) {
        cur[t] = estart + excl;
        int node = k * BSIZE + t;
        if (node < n) {
            rowptr[node] = estart + excl;
            degi[node]   = v;
            dis[node]    = rsqrtf((float)(v + 1));
        }
    }
    __syncthreads();
    for (int i = estart + t; i < eend; i += 256) {
        int w = ebuf[i];
        int pos = atomicAdd(&cur[w & (BSIZE - 1)], 1);
        ebuf2[pos] = w;      // packed (src<<7 | dlow), dst-sorted
    }
}

// h1s = fp16( (x @ W1) * dis ) — outer-product GEMM, block tile 64x64, K=128.
#define SA 132
__global__ __launch_bounds__(256) void k_gemm1(
        const float* __restrict__ x, const float* __restrict__ W1,
        const float* __restrict__ dis, __half* __restrict__ h1s, int n) {
    __shared__ float Xs[64 * SA];    // 33 KB
    __shared__ float Ws[128 * 64];   // 32 KB
    int t = threadIdx.x;
    int nbase = blockIdx.x * 64;
    for (int i = t; i < 2048; i += 256)
        ((float4*)Ws)[i] = ((const float4*)W1)[i];
    for (int i = t; i < 2048; i += 256) {
        int row = i >> 5, q = i & 31;
        int r = nbase + row; if (r >= n) r = n - 1;
        float4 v = ((const float4*)(x + (size_t)r * 128))[q];
        *(float4*)&Xs[row * SA + q * 4] = v;
    }
    __syncthreads();
    int wid = t >> 6, lane = t & 63;
    int lx = lane & 7, ly = lane >> 3;
    int wm = wid & 1, wn = wid >> 1;
    int row0 = wm * 32 + ly * 4;
    int col0 = wn * 32 + lx * 4;
    float4 acc0 = {0.f,0.f,0.f,0.f}, acc1 = acc0, acc2 = acc0, acc3 = acc0;
#pragma unroll 4
    for (int k4 = 0; k4 < 32; ++k4) {
        int k = k4 * 4;
        float4 a0 = *(const float4*)&Xs[(row0 + 0) * SA + k];
        float4 a1 = *(const float4*)&Xs[(row0 + 1) * SA + k];
        float4 a2 = *(const float4*)&Xs[(row0 + 2) * SA + k];
        float4 a3 = *(const float4*)&Xs[(row0 + 3) * SA + k];
        float4 b0 = *(const float4*)&Ws[(k + 0) * 64 + col0];
        float4 b1 = *(const float4*)&Ws[(k + 1) * 64 + col0];
        float4 b2 = *(const float4*)&Ws[(k + 2) * 64 + col0];
        float4 b3 = *(const float4*)&Ws[(k + 3) * 64 + col0];
        f4fma(acc0, a0.x, b0); f4fma(acc0, a0.y, b1); f4fma(acc0, a0.z, b2); f4fma(acc0, a0.w, b3);
        f4fma(acc1, a1.x, b0); f4fma(acc1, a1.y, b1); f4fma(acc1, a1.z, b2); f4fma(acc1, a1.w, b3);
        f4fma(acc2, a2.x, b0); f4fma(acc2, a2.y, b1); f4fma(acc2, a2.z, b2); f4fma(acc2, a2.w, b3);
        f4fma(acc3, a3.x, b0); f4fma(acc3, a3.y, b1); f4fma(acc3, a3.z, b2); f4fma(acc3, a3.w, b3);
    }
    int grow = nbase + row0;
#pragma unroll
    for (int r = 0; r < 4; ++r) {
        int rr = grow + r;
        if (rr < n) {
            float d = dis[rr];
            float4 o = (r == 0) ? acc0 : (r == 1) ? acc1 : (r == 2) ? acc2 : acc3;
            o.x *= d; o.y *= d; o.z *= d; o.w *= d;
            h4store(&h1s[(size_t)rr * 64 + col0], o);
        }
    }
}

// Layer-1 aggregation + relu/b1 + gemm2, all in-wave.  Wave per dst node.
// fp16 row = 128 B = 8 lanes x 16 B: eg = lane>>3 (8 edge slots), fq =
// (lane&7)*8 halves; one dwordx4 covers 8 edges per instruction.
// xor-8/16/32 reduce -> lanes 0-7 hold the h1r row (8 feats each) -> relu ->
// LDS row -> in-wave gemm2 (W2 column in registers) -> h2s (fp16).
__global__ __launch_bounds__(256) void k_agg12(
        const __half* __restrict__ h1s, const int* __restrict__ ents,
        const int* __restrict__ rowptr, const int* __restrict__ degi,
        const float* __restrict__ dis, const float* __restrict__ b1,
        const float* __restrict__ W2, __half* __restrict__ h2s, int n) {
    __shared__ float h1row[4][72];
    int wid = threadIdx.x >> 6, lane = threadIdx.x & 63;
    int v = blockIdx.x * 4 + wid;
    int vc = min(v, n - 1);            // no early return (syncthreads below)
    int start = rowptr[vc], cnt = degi[vc];
    int eg = lane >> 3;
    int fq = (lane & 7) * 8;           // half-index of this lane's 8 features
    int c = lane & 31, hh = lane >> 5;
    // preload W2 column c, k-range [hh*32, hh*32+32) -> 32 VGPRs
    float w2r[32];
#pragma unroll
    for (int j = 0; j < 32; ++j)
        w2r[j] = W2[(hh * 32 + j) * 32 + c];
    float4 accA = {0.f, 0.f, 0.f, 0.f}, accB = accA;
    if (cnt > 0 && cnt <= 64) {
        int pre = ents[start + min(lane, cnt - 1)];
        int ng = cnt >> 3;
#pragma unroll 2
        for (int g = 0; g < ng; ++g) {
            unsigned s = ((unsigned)__shfl(pre, g * 8 + eg)) >> BSHIFT;
            float4 a, b; h8load(&h1s[(size_t)s * 64 + fq], a, b);
            f4add(accA, a); f4add(accB, b);
        }
        int rem = cnt & 7, j0 = cnt & ~7;
        if (rem) {
            unsigned s = ((unsigned)__shfl(pre, j0 + (eg < rem ? eg : 0))) >> BSHIFT;
            float4 a, b; h8load(&h1s[(size_t)s * 64 + fq], a, b);
            if (eg < rem) { f4add(accA, a); f4add(accB, b); }
        }
    } else if (cnt > 64) {
        int j = 0;
        for (; j + 8 <= cnt; j += 8) {
            unsigned s = ((unsigned)ents[start + j + eg]) >> BSHIFT;
            float4 a, b; h8load(&h1s[(size_t)s * 64 + fq], a, b);
            f4add(accA, a); f4add(accB, b);
        }
        int rem = cnt - j;
        if (rem) {
            unsigned s = ((unsigned)ents[start + j + (eg < rem ? eg : 0)]) >> BSHIFT;
            float4 a, b; h8load(&h1s[(size_t)s * 64 + fq], a, b);
            if (eg < rem) { f4add(accA, a); f4add(accB, b); }
        }
    }
    if (eg == 0) {                     // self loop
        float4 a, b; h8load(&h1s[(size_t)vc * 64 + fq], a, b);
        f4add(accA, a); f4add(accB, b);
    }
    f4red(accA, 8);  f4red(accB, 8);
    f4red(accA, 16); f4red(accB, 16);
    f4red(accA, 32); f4red(accB, 32);
    float d = dis[vc];
    if (eg == 0) {
        float4 bq0 = *(const float4*)&b1[fq];
        float4 bq1 = *(const float4*)&b1[fq + 4];
        float4 o0, o1;
        o0.x = fmaxf(fmaf(d, accA.x, bq0.x), 0.f);
        o0.y = fmaxf(fmaf(d, accA.y, bq0.y), 0.f);
        o0.z = fmaxf(fmaf(d, accA.z, bq0.z), 0.f);
        o0.w = fmaxf(fmaf(d, accA.w, bq0.w), 0.f);
        o1.x = fmaxf(fmaf(d, accB.x, bq1.x), 0.f);
        o1.y = fmaxf(fmaf(d, accB.y, bq1.y), 0.f);
        o1.z = fmaxf(fmaf(d, accB.z, bq1.z), 0.f);
        o1.w = fmaxf(fmaf(d, accB.w, bq1.w), 0.f);
        *(float4*)&h1row[wid][fq] = o0;
        *(float4*)&h1row[wid][fq + 4] = o1;
    }
    __syncthreads();     // orders each wave's LDS row write before its reads
    // gemm2 in-wave: lane computes h2[c] partial over its k-half
    float p = 0.f;
#pragma unroll
    for (int j = 0; j < 32; j += 4) {
        float4 hv = *(const float4*)&h1row[wid][hh * 32 + j];
        p = fmaf(hv.x, w2r[j + 0], p);
        p = fmaf(hv.y, w2r[j + 1], p);
        p = fmaf(hv.z, w2r[j + 2], p);
        p = fmaf(hv.w, w2r[j + 3], p);
    }
    p += __shfl_xor(p, 32);
    if (hh == 0 && v < n) h2s[(size_t)v * 32 + c] = __float2half(p * d);
}

// layer-2 aggregation + relu + FC head.  fp16 row = 64 B = 4 lanes x 16 B:
// eg = lane>>2 (16 edge slots), fq = (lane&3)*8 halves; one dwordx4 covers
// 16 edges per instruction.  xor-4/8/16/32 reduce; FC in lanes 0-3.
__global__ void k_agg2(const __half* __restrict__ h2s, const int* __restrict__ ents,
                       const int* __restrict__ rowptr, const int* __restrict__ degi,
                       const float* __restrict__ dis, const float* __restrict__ b2,
                       const float* __restrict__ Wfc, const float* __restrict__ bfc,
                       float* __restrict__ out, int n) {
    int wid = threadIdx.x >> 6, lane = threadIdx.x & 63;
    int v = blockIdx.x * 4 + wid;
    if (v >= n) return;
    int start = rowptr[v], cnt = degi[v];
    int eg = lane >> 2;
    int fq = (lane & 3) * 8;
    float4 accA = {0.f, 0.f, 0.f, 0.f}, accB = accA;
    if (cnt > 0 && cnt <= 64) {
        int pre = ents[start + min(lane, cnt - 1)];
        int ng = cnt >> 4;
#pragma unroll 2
        for (int g = 0; g < ng; ++g) {
            unsigned s = ((unsigned)__shfl(pre, g * 16 + eg)) >> BSHIFT;
            float4 a, b; h8load(&h2s[(size_t)s * 32 + fq], a, b);
            f4add(accA, a); f4add(accB, b);
        }
        int rem = cnt & 15, j0 = cnt & ~15;
        if (rem) {
            unsigned s = ((unsigned)__shfl(pre, j0 + (eg < rem ? eg : 0))) >> BSHIFT;
            float4 a, b; h8load(&h2s[(size_t)s * 32 + fq], a, b);
            if (eg < rem) { f4add(accA, a); f4add(accB, b); }
        }
    } else if (cnt > 64) {
        int j = 0;
        for (; j + 16 <= cnt; j += 16) {
            unsigned s = ((unsigned)ents[start + j + eg]) >> BSHIFT;
            float4 a, b; h8load(&h2s[(size_t)s * 32 + fq], a, b);
            f4add(accA, a); f4add(accB, b);
        }
        int rem = cnt - j;
        if (rem) {
            unsigned s = ((unsigned)ents[start + j + (eg < rem ? eg : 0)]) >> BSHIFT;
            float4 a, b; h8load(&h2s[(size_t)s * 32 + fq], a, b);
            if (eg < rem) { f4add(accA, a); f4add(accB, b); }
        }
    }
    if (eg == 0) {                     // self loop (lanes 0-3)
        float4 a, b; h8load(&h2s[(size_t)v * 32 + fq], a, b);
        f4add(accA, a); f4add(accB, b);
    }
    f4red(accA, 4);  f4red(accB, 4);
    f4red(accA, 8);  f4red(accB, 8);
    f4red(accA, 16); f4red(accB, 16);
    f4red(accA, 32); f4red(accB, 32);
    float p = 0.f;
    if (eg == 0) {
        float d = dis[v];
        float4 bq0 = *(const float4*)&b2[fq];
        float4 bq1 = *(const float4*)&b2[fq + 4];
        float4 wq0 = *(const float4*)&Wfc[fq];
        float4 wq1 = *(const float4*)&Wfc[fq + 4];
        p  = fmaxf(fmaf(d, accA.x, bq0.x), 0.f) * wq0.x;
        p += fmaxf(fmaf(d, accA.y, bq0.y), 0.f) * wq0.y;
        p += fmaxf(fmaf(d, accA.z, bq0.z), 0.f) * wq0.z;
        p += fmaxf(fmaf(d, accA.w, bq0.w), 0.f) * wq0.w;
        p += fmaxf(fmaf(d, accB.x, bq1.x), 0.f) * wq1.x;
        p += fmaxf(fmaf(d, accB.y, bq1.y), 0.f) * wq1.y;
        p += fmaxf(fmaf(d, accB.z, bq1.z), 0.f) * wq1.z;
        p += fmaxf(fmaf(d, accB.w, bq1.w), 0.f) * wq1.w;
    }
    p += __shfl_xor(p, 1); p += __shfl_xor(p, 2);
    if (lane == 0) out[v] = p + bfc[0];
}

extern "C" void kernel_launch(void* const* d_in, const int* in_sizes, int n_in,
                              void* d_out, int out_size, void* d_ws, size_t ws_size,
                              hipStream_t stream) {
    const float* x   = (const float*)d_in[0];
    const int*   ei  = (const int*)d_in[1];
    const float* W1  = (const float*)d_in[2];
    const float* b1  = (const float*)d_in[3];
    const float* W2  = (const float*)d_in[4];
    const float* b2  = (const float*)d_in[5];
    const float* Wfc = (const float*)d_in[6];
    const float* bfc = (const float*)d_in[7];
    float* out = (float*)d_out;

    const int n = in_sizes[0] / 128;       // 100000
    const int e = in_sizes[1] / 2;         // 3200000
    const int* src = ei;
    const int* dst = ei + e;

    const int nbuck = (n + BSIZE - 1) / BSIZE;           // 782
    const int m = nbuck * B1;                            // 200192
    const int echunk = (e + B1 - 1) / B1;                // 12500

    char* p = (char*)d_ws;
    size_t off = 0;
    auto carve = [&](size_t bytes) { void* r = p + off; off = (off + bytes + 255) & ~(size_t)255; return r; };
    int*   ghist   = (int*)  carve((size_t)m * 4);
    int*   ghist_s = (int*)  carve((size_t)m * 4);
    int*   part    = (int*)  carve(256 * 4);
    float* dis     = (float*)carve((size_t)n * 4);
    int*   rowptr  = (int*)  carve((size_t)n * 4);
    int*   degi    = (int*)  carve((size_t)n * 4);
    int*   ebuf2   = (int*)  carve((size_t)e * 4);
    __half* h2s    = (__half*)carve((size_t)n * 32 * 2);
    void*  ebuf_or_h1s = carve((size_t)e * 4);           // ebuf(E*4) aliases h1s(N*64*2)
    int*    ebuf = (int*)ebuf_or_h1s;
    __half* h1s  = (__half*)ebuf_or_h1s;
    (void)ws_size;

    const int nblk_scan = (m + SCAN_CHUNK - 1) / SCAN_CHUNK;   // 196 (<=256)
    const size_t lds_buck = (size_t)nbuck * 4;

    k_hist<<<B1, 256, lds_buck, stream>>>(dst, ghist, e, echunk, nbuck);
    k_gscan1<<<nblk_scan, 256, 0, stream>>>(ghist, part, m);
    k_gscan2<<<nblk_scan, 256, 0, stream>>>(ghist, part, ghist_s, m, nblk_scan);
    k_binscatter<<<B1, 256, lds_buck, stream>>>(src, dst, ghist_s, ebuf, e, echunk, nbuck);
    k_csr<<<nbuck, 256, 0, stream>>>(ebuf, ghist_s, ebuf2, rowptr, degi, dis, n, e, nbuck);
    k_gemm1<<<(n + 63) / 64, 256, 0, stream>>>(x, W1, dis, h1s, n);
    k_agg12<<<(n + 3) / 4, 256, 0, stream>>>(h1s, ebuf2, rowptr, degi, dis, b1, W2, h2s, n);
    k_agg2<<<(n + 3) / 4, 256, 0, stream>>>(h2s, ebuf2, rowptr, degi, dis, b2, Wfc, bfc, out, n);
}